// Round 9
// baseline (578.641 us; speedup 1.0000x reference)
//
#include <hip/hip_runtime.h>
#include <cstdint>

typedef unsigned short u16;
typedef short short8 __attribute__((ext_vector_type(8)));
typedef float floatx4 __attribute__((ext_vector_type(4)));

#define B_ 4
#define L_ 2048
#define D_ 512
#define P_ 128
#define V_ 8
#define BL (B_ * L_)        // 8192
#define NC_ 128             // KV chunks per batch
#define CH_ 16              // KV chunk length
#define PI_F 3.14159265358979323846f

__device__ inline u16 f2b(float f) {
    unsigned u = __float_as_uint(f);
    unsigned r = u + 0x7FFFu + ((u >> 16) & 1u);
    return (u16)(r >> 16);
}
__device__ inline float b2f(u16 h) {
    return __uint_as_float(((unsigned)h) << 16);
}
__device__ inline float gelu_f(float v) {
    return 0.5f * v * (1.0f + erff(v * 0.70710678118654752f));
}
__device__ inline float sigm(float v) {
    return 1.0f / (1.0f + __expf(-v));
}
__device__ inline float tanh_fast(float v) {
    return 1.0f - 2.0f / (1.0f + __expf(2.0f * v));
}

// async global->LDS, 16B per lane. LDS dest is wave-uniform base + lane*16.
__device__ inline void async16(const u16* g, u16* l) {
    __builtin_amdgcn_global_load_lds(
        (const __attribute__((address_space(1))) unsigned int*)g,
        (__attribute__((address_space(3))) unsigned int*)l, 16, 0, 0);
}

extern __shared__ u16 smem_dyn[];   // 36864 B: 3-slot ring of (A 8KB + B 4KB)

// ---------------------------------------------------------------------------
// 128x64-tile bf16 MFMA GEMM body, BK=32, COMPILE-TIME epilogue.
// R9: same per-wave shape as R5/R8 (64x32 output, acc[4][2], XOR-swizzle,
// frag double-buffer, 3-slot ring, counted vmcnt), but BN 128->64 with
// 256-thread blocks (4 waves, 2x2 wave grid):
//   * grid doubles -> o1 (64,16)=1024 blocks = 4 blocks/CU exactly
//     (LDS 36KB/block, 160/36=4), still 16 waves/CU;
//   * 4 independent barrier groups per CU instead of 2 -> finer
//     LDS-burst/MFMA anti-phasing (m114 inter-block overlap);
//   * o2 grid 256->512 (was 1 block/CU).
//   HBM unchanged: extra A re-reads are L2/L3 hits (A panels L3-resident).
// Staging per wave per stage: 2 async16 for A rows [32w,32w+32), 1 for B
// rows [16w,16w+16).  vmcnt: steady outstanding = 2 stages x 3 = 6 ->
// vmcnt(3) confirms stage t+1; prologue 9 -> vmcnt(6); tails vmcnt(0).
// WAR: own-wave frag reads drained by pre-barrier lgkm(0); cross-wave by
// the barrier.  RAW: per-wave counted vmcnt pre-barrier + barrier.
// 256 threads = 4 waves.  C[m,n] = epi( sum_k A[m,k]*W[n,k] + bias[n] ).
// Requires nsteps = K/32 EVEN and >= 4 (call sites: K in {128,512,1024,2560}).
// ---------------------------------------------------------------------------
enum { EPI_F32 = 0, EPI_BF16 = 1, EPI_GELU_BF16 = 2, EPI_RESID_F32 = 3,
       EPI_PASS1 = 4, EPI_ATOMIC = 5 };

template <int EPI>
__device__ __forceinline__ void gemm_body(
    const u16* __restrict__ A, int lda,
    const u16* __restrict__ W, int ldw,
    const float* __restrict__ bias,
    void* __restrict__ Cout, int ldc, int N, int K,
    const float* __restrict__ resid, int mt, int nt)
{
    const int tid  = threadIdx.x;
    const int lane = tid & 63;
    const int wid  = tid >> 6;               // 0..3
    const int wm   = wid & 1, wn = wid >> 1; // 2 x 2 wave grid
    const int l16  = lane & 15, quad = lane >> 4;
    const int rswz = (l16 >> 1) & 3;          // read-side cg XOR ((row>>1)&3)

    floatx4 acc[4][2] = {};

    const u16* Ab = A + (size_t)(mt * 128) * lda;
    const u16* Wb = W + (size_t)(nt * 64) * ldw;

    const int srow = lane >> 2;
    // source column pre-swizzled so linear LDS write lands swizzled data
    const int scol = ((lane & 3) ^ ((srow >> 1) & 3)) * 8;
    // wave w stages A rows [32w,32w+32) (2 async16) and B rows [16w,16w+16)
    const u16* ga0 = Ab + (size_t)(wid * 32 + srow) * lda + scol;
    const u16* ga1 = Ab + (size_t)(wid * 32 + 16 + srow) * lda + scol;
    const u16* gb0 = Wb + (size_t)(wid * 16 + srow) * ldw + scol;
    const int lA = wid * 1024;               // u16 offsets (A: 2 chunks of 512)
    const int lB = 4096 + wid * 512;

    const int nsteps = K >> 5;

    auto stage = [&](int t, int s) {
        u16* base = smem_dyn + s * 6144;      // 12KB slot = 6144 u16
        const int ko = t * 32;
        async16(ga0 + ko, base + lA);
        async16(ga1 + ko, base + lA + 512);
        async16(gb0 + ko, base + lB);
    };

    auto readfrag = [&](int slot, short8 (&a)[4], short8 (&b)[2]) {
        const u16* As = smem_dyn + slot * 6144;
        const u16* Bs = As + 4096;
#pragma unroll
        for (int i = 0; i < 4; i++)
            a[i] = *(const short8*)(&As[(wm * 64 + i * 16 + l16) * 32 + (quad ^ rswz) * 8]);
#pragma unroll
        for (int j = 0; j < 2; j++)
            b[j] = *(const short8*)(&Bs[(wn * 32 + j * 16 + l16) * 32 + (quad ^ rswz) * 8]);
    };

    auto mfma8 = [&](short8 (&a)[4], short8 (&b)[2]) {
        __builtin_amdgcn_s_setprio(1);
#pragma unroll
        for (int i = 0; i < 4; i++)
#pragma unroll
            for (int j = 0; j < 2; j++)
                acc[i][j] = __builtin_amdgcn_mfma_f32_16x16x32_bf16(a[i], b[j], acc[i][j], 0, 0, 0);
        __builtin_amdgcn_s_setprio(0);
    };

    // prologue: fill the ring (3 loads/stage -> 9 outstanding), confirm stage 0
    stage(0, 0);
    if (nsteps > 1) stage(1, 1);
    if (nsteps > 2) stage(2, 2);
    if (nsteps > 2)      asm volatile("s_waitcnt vmcnt(6)" ::: "memory");
    else if (nsteps > 1) asm volatile("s_waitcnt vmcnt(3)" ::: "memory");
    else                 asm volatile("s_waitcnt vmcnt(0)" ::: "memory");
    __builtin_amdgcn_s_barrier();
    asm volatile("" ::: "memory");

    short8 aE[4], bE[2], aO[4], bO[2];
    readfrag(0, aE, bE);

    for (int t = 0; t < nsteps; t += 2) {
        // ---- even iter: consume set E, prefetch set O ----
        asm volatile("s_waitcnt lgkmcnt(0)" ::: "memory");   // frag t in regs
        if (t + 2 < nsteps)      asm volatile("s_waitcnt vmcnt(3)" ::: "memory");
        else if (t + 1 < nsteps) asm volatile("s_waitcnt vmcnt(0)" ::: "memory");
        __builtin_amdgcn_s_barrier();
        asm volatile("" ::: "memory");
        if (t + 3 < nsteps) stage(t + 3, t % 3);
        if (t + 1 < nsteps) readfrag((t + 1) % 3, aO, bO);
        mfma8(aE, bE);
        // ---- odd iter: consume set O, prefetch set E ----
        const int t1 = t + 1;                                 // < nsteps (even nsteps)
        asm volatile("s_waitcnt lgkmcnt(0)" ::: "memory");
        if (t1 + 2 < nsteps)      asm volatile("s_waitcnt vmcnt(3)" ::: "memory");
        else if (t1 + 1 < nsteps) asm volatile("s_waitcnt vmcnt(0)" ::: "memory");
        __builtin_amdgcn_s_barrier();
        asm volatile("" ::: "memory");
        if (t1 + 3 < nsteps) stage(t1 + 3, t1 % 3);
        if (t1 + 1 < nsteps) readfrag((t1 + 1) % 3, aE, bE);
        mfma8(aO, bO);
    }

#pragma unroll
    for (int i = 0; i < 4; i++) {
#pragma unroll
        for (int j = 0; j < 2; j++) {
#pragma unroll
            for (int r = 0; r < 4; r++) {
                int grow = mt * 128 + wm * 64 + i * 16 + quad * 4 + r;
                int gcol = nt * 64 + wn * 32 + j * 16 + l16;
                if (gcol < N) {
                    float v = acc[i][j][r] + (bias ? bias[gcol] : 0.0f);
                    size_t off = (size_t)grow * ldc + gcol;
                    if (EPI == EPI_F32)            ((float*)Cout)[off] = v;
                    else if (EPI == EPI_BF16)      ((u16*)Cout)[off] = f2b(v);
                    else if (EPI == EPI_GELU_BF16) ((u16*)Cout)[off] = f2b(gelu_f(v));
                    else if (EPI == EPI_PASS1) {
                        float vv = (gcol >= 512 && gcol < 1024) ? gelu_f(v) : v;
                        ((u16*)Cout)[off] = f2b(vv);
                    }
                    else if (EPI == EPI_RESID_F32) ((float*)Cout)[off] = v + resid[off];
                    else                           atomicAdd(&((float*)Cout)[off], v);
                }
            }
        }
    }
}

// generic GEMM; grid.z = split-K slice (A,W advance by kz*K along k; bias slice 0)
template <int EPI>
__global__ __launch_bounds__(256)
void gemm256(const u16* __restrict__ A, int lda,
             const u16* __restrict__ W, int ldw,
             const float* __restrict__ bias,
             void* __restrict__ C, int ldc, int N, int K,
             const float* __restrict__ resid)
{
    int kz = blockIdx.z;
    gemm_body<EPI>(A + (size_t)kz * K, lda, W + (size_t)kz * K, ldw,
                   kz == 0 ? bias : nullptr, C, ldc, N, K, resid,
                   blockIdx.x, blockIdx.y);
}

// pass1 (N=2560, y 0..39) + ke/ve/sg (N=144, y 40..42) + conv proj (y 43..50)
__global__ __launch_bounds__(256)
void mega1(const u16* __restrict__ xcat, const u16* __restrict__ convg,
           const u16* __restrict__ wcat1, const float* __restrict__ bcat1,
           const u16* __restrict__ kesgw, const float* __restrict__ kesgb,
           const u16* __restrict__ cpw, const float* __restrict__ cp_b,
           u16* __restrict__ out1, float* __restrict__ kesgo, u16* __restrict__ combined)
{
    int y = blockIdx.y, mt = blockIdx.x;
    if (y < 40)
        gemm_body<EPI_PASS1>(xcat, 1024, wcat1, 512, bcat1, out1, 2560, 2560, 512, nullptr, mt, y);
    else if (y < 43)
        gemm_body<EPI_F32>(xcat, 1024, kesgw, 512, kesgb, kesgo, 144, 144, 512, nullptr, mt, y - 40);
    else
        gemm_body<EPI_BF16>(convg, 512, cpw, 512, cp_b, combined, 2560, 512, 512, nullptr, mt, y - 43);
}

// pos_out (y 0..7) + sk0 (y 8..15)
__global__ __launch_bounds__(256)
void mega2(const u16* __restrict__ posret, const u16* __restrict__ xcat,
           const u16* __restrict__ m1ow, const float* __restrict__ m1o_b,
           const u16* __restrict__ sk0w, const float* __restrict__ sk0_b,
           u16* __restrict__ combined, u16* __restrict__ sk0g)
{
    int y = blockIdx.y, mt = blockIdx.x;
    if (y < 8)
        gemm_body<EPI_BF16>(posret, 512, m1ow, 512, m1o_b, combined + 512, 2560, 512, 512, nullptr, mt, y);
    else
        gemm_body<EPI_GELU_BF16>(xcat, 1024, sk0w, 1024, sk0_b, sk0g, 512, 512, 1024, nullptr, mt, y - 8);
}

// ---------------------------------------------------------------------------
// Weight prep: cast fp32 weights -> bf16, build concatenations + pads.
// ---------------------------------------------------------------------------
__global__ __launch_bounds__(256)
void prep_weights(const float* tw, const float* pi0, const float* m1v, const float* mag, const float* qo,
                  const float* ke, const float* ve, const float* sg,
                  const float* pi2, const float* cp, const float* sk0, const float* sk2,
                  const float* m1o, const float* o1, const float* o2,
                  const float* tw_b, const float* pi0_b, const float* m1v_b, const float* mag_b, const float* qo_b,
                  const float* ke_b, const float* ve_b, const float* sg_b,
                  u16* wcat1, float* bcat1, u16* kesgw, float* kesgb,
                  u16* pi2w, u16* cpw, u16* sk0w, u16* sk2w, u16* m1ow, u16* o1w, u16* o2w)
{
    int idx = blockIdx.x * 256 + threadIdx.x;
    const int n0 = 2560 * 512;
    const int n1 = n0 + 256 * 512;
    const int n2 = n1 + 512 * 512;
    const int n3 = n2 + 512 * 512;
    const int n4 = n3 + 512 * 1024;
    const int n5 = n4 + 128 * 512;
    const int n6 = n5 + 512 * 512;
    const int n7 = n6 + 1024 * 2560;
    const int n8 = n7 + 512 * 1024;
    const int n9 = n8 + 2560;
    const int n10 = n9 + 256;
    if (idx < n0) {
        int r = idx >> 9, k = idx & 511;
        const float* s = (r < 512) ? tw : (r < 1024) ? pi0 : (r < 1536) ? m1v : (r < 2048) ? mag : qo;
        wcat1[idx] = f2b(s[(r & 511) * 512 + k]);
    } else if (idx < n1) {
        int i = idx - n0; int r = i >> 9, k = i & 511;
        float v;
        if (r < 128)      v = ke[r * 512 + k];
        else if (r < 136) v = ve[(r - 128) * 512 + k];
        else if (r == 136) v = sg[k];
        else               v = 0.0f;
        kesgw[i] = f2b(v);
    }
    else if (idx < n2) { int i = idx - n1; pi2w[i] = f2b(pi2[i]); }
    else if (idx < n3) { int i = idx - n2; cpw[i]  = f2b(cp[i]); }
    else if (idx < n4) { int i = idx - n3; sk0w[i] = f2b(sk0[i]); }
    else if (idx < n5) { int i = idx - n4; sk2w[i] = f2b(sk2[i]); }
    else if (idx < n6) { int i = idx - n5; m1ow[i] = f2b(m1o[i]); }
    else if (idx < n7) { int i = idx - n6; o1w[i]  = f2b(o1[i]); }
    else if (idx < n8) { int i = idx - n7; o2w[i]  = f2b(o2[i]); }
    else if (idx < n9) {
        int i = idx - n8;
        const float* s = (i < 512) ? tw_b : (i < 1024) ? pi0_b : (i < 1536) ? m1v_b : (i < 2048) ? mag_b : qo_b;
        bcat1[i] = s[i & 511];
    } else if (idx < n10) {
        int i = idx - n9;
        kesgb[i] = (i < 128) ? ke_b[i] : (i < 136) ? ve_b[i - 128] : (i == 136) ? sg_b[0] : 0.0f;
    }
}

// depthwise causal conv (K=4) gated branch + cast x into xcat cols [0,512)
__global__ __launch_bounds__(256)
void conv_gate(const float* __restrict__ x,
               const float* __restrict__ lcw, const float* __restrict__ lcb,
               const float* __restrict__ cgw, const float* __restrict__ cgb,
               u16* __restrict__ out, u16* __restrict__ xcat)
{
    int idx = blockIdx.x * 256 + threadIdx.x;   // over BL*512
    int d = idx & 511; int bl = idx >> 9;
    int l = bl & (L_ - 1); int b = bl >> 11;
    float a0 = 0.f, a1 = 0.f, xv3 = 0.f;
#pragma unroll
    for (int k = 0; k < 4; k++) {
        int ls = l - 3 + k;
        if (ls >= 0) {
            float xv = x[((size_t)(b * L_ + ls)) * 512 + d];
            if (k == 3) xv3 = xv;
            a0 += xv * lcw[d * 4 + k];
            a1 += xv * cgw[d * 4 + k];
        }
    }
    a0 += lcb[d];
    a1 = sigm(a1 + cgb[d]);
    out[idx] = f2b(a0 * a1);
    xcat[(size_t)bl * 1024 + d] = f2b(xv3);
}

// ---------------------------------------------------------------------------
// scan_a body (256-thread version): per-chunk sums of omega/mag/x.
// blk = b(4) x dt(8) x nc(16).  4 groups of 64 lanes, 32 rows each.
// ---------------------------------------------------------------------------
__device__ __forceinline__ void scan_a_body(
    int blk, const u16* __restrict__ out1, const float* __restrict__ x,
    const float* __restrict__ oscale, const float* __restrict__ msc,
    float* __restrict__ cs_o, float* __restrict__ cs_x, float* __restrict__ cs_m)
{
    int nc = blk & 15, dt = (blk >> 4) & 7, b = blk >> 7;
    int t = threadIdx.x; int dl = t & 63, lg = t >> 6;
    int d = dt * 64 + dl;
    float os = fabsf(oscale[d]);
    float ms = fabsf(msc[0]);
    float so = 0.f, sx = 0.f, sm = 0.f;
    int l0 = nc * 128 + lg * 32;
    for (int i = 0; i < 32; i++) {
        size_t r = (size_t)(b * L_ + l0 + i);
        so += b2f(out1[r * 2560 + d]) * os;
        sm += sigm(b2f(out1[r * 2560 + 1536 + d])) * ms;
        sx += x[r * 512 + d];
    }
    __shared__ float sh[3][4][64];
    sh[0][lg][dl] = so; sh[1][lg][dl] = sx; sh[2][lg][dl] = sm;
    __syncthreads();
    if (t < 64) {
        float a = 0.f, xx = 0.f, m = 0.f;
        for (int g = 0; g < 4; g++) { a += sh[0][g][t]; xx += sh[1][g][t]; m += sh[2][g][t]; }
        size_t o = ((size_t)(b * 16 + nc)) * 512 + dt * 64 + t;
        cs_o[o] = a; cs_x[o] = xx; cs_m[o] = m;
    }
}

// store-gate scan: wave w handles batch w (256-thread block, 4 waves).
__device__ __forceinline__ void gate_body(const float* __restrict__ kesgo,
                                          float* __restrict__ gni)
{
    int b = threadIdx.x >> 6; int lane = threadIdx.x & 63;
    float v[32]; float s = 0.f;
#pragma unroll
    for (int i = 0; i < 32; i++) {
        int l = lane * 32 + i;
        v[i] = sigm(kesgo[((size_t)(b * L_ + l)) * 144 + 136]);
        s += v[i];
    }
    float sc = s;
#pragma unroll
    for (int ofs = 1; ofs < 64; ofs <<= 1) {
        float t = __shfl_up(sc, ofs, 64);
        if (lane >= ofs) sc += t;
    }
    float run = sc - s;   // exclusive prefix
#pragma unroll
    for (int i = 0; i < 32; i++) {
        run += v[i];
        gni[b * L_ + lane * 32 + i] = rsqrtf(fmaxf(run, 1.0f));
    }
}

// fused: pi2 GEMM (blocks 0..511, 8 col-tiles) + scan_a (512..1023) + gate (1024)
__global__ __launch_bounds__(256)
void stage2(const u16* __restrict__ out1, const u16* __restrict__ pi2w,
            const float* __restrict__ pi2_b, u16* __restrict__ phib,
            const float* __restrict__ x, const float* __restrict__ oscale,
            const float* __restrict__ msc,
            float* __restrict__ cs_o, float* __restrict__ cs_x, float* __restrict__ cs_m,
            const float* __restrict__ kesgo, float* __restrict__ gni)
{
    int blk = blockIdx.x;
    if (blk < 512)
        gemm_body<EPI_BF16>(out1 + 512, 2560, pi2w, 512, pi2_b, phib, 512, 512, 512,
                            nullptr, blk & 63, blk >> 6);
    else if (blk < 1024)
        scan_a_body(blk - 512, out1, x, oscale, msc, cs_o, cs_x, cs_m);
    else
        gate_body(kesgo, gni);
}

// scan_c (512 threads, 16 rows/thread — R8 latency-regime widening, kept).
__global__ __launch_bounds__(512)
void scan_c(const u16* __restrict__ out1, const u16* __restrict__ phib,
            const float* __restrict__ oscale, const float* __restrict__ msc,
            const float* __restrict__ cs_o,
            float* __restrict__ phi, float* __restrict__ cs_wc, float* __restrict__ cs_ws)
{
    int blk = blockIdx.x;
    int nc = blk & 15, dt = (blk >> 4) & 7, b = blk >> 7;
    int t = threadIdx.x; int dl = t & 63, lg = t >> 6;   // lg 0..7
    int d = dt * 64 + dl;
    float os = fabsf(oscale[d]);
    float ms = fabsf(msc[0]);
    int l0 = nc * 128 + lg * 16;
    float so = 0.f;
    for (int i = 0; i < 16; i++) {
        size_t r = (size_t)(b * L_ + l0 + i);
        so += b2f(out1[r * 2560 + d]) * os;
    }
    __shared__ float sh[8][64];
    __shared__ float shw[2][8][64];
    sh[lg][dl] = so;
    __syncthreads();
    float pre = 0.f;
    for (int p = 0; p < nc; p++) pre += cs_o[((size_t)(b * 16 + p)) * 512 + d];
    for (int g = 0; g < lg; g++) pre += sh[g][dl];
    float cum = pre, swc = 0.f, sws = 0.f;
    for (int i = 0; i < 16; i++) {
        size_t r = (size_t)(b * L_ + l0 + i);
        cum += b2f(out1[r * 2560 + d]) * os;
        float ph = b2f(phib[r * 512 + d]) + cum;
        phi[r * 512 + d] = ph;
        float mg = sigm(b2f(out1[r * 2560 + 1536 + d])) * ms;
        float wv = mg * b2f(out1[r * 2560 + 1024 + d]);
        float s = __sinf(ph), c = __cosf(ph);
        swc += wv * c; sws += wv * s;
    }
    shw[0][lg][dl] = swc; shw[1][lg][dl] = sws;
    __syncthreads();
    if (t < 64) {
        float a = 0.f, bb = 0.f;
        for (int g = 0; g < 8; g++) { a += shw[0][g][t]; bb += shw[1][g][t]; }
        size_t o = ((size_t)(b * 16 + nc)) * 512 + dt * 64 + t;
        cs_wc[o] = a; cs_ws[o] = bb;
    }
}

// scan_e (512 threads, 16 rows/thread — R8 widening, kept).
__global__ __launch_bounds__(512)
void scan_e(const u16* __restrict__ out1, const float* __restrict__ phi,
            const float* __restrict__ x, const float* __restrict__ msc,
            const float* __restrict__ cs_m, const float* __restrict__ cs_x,
            const float* __restrict__ cs_wc, const float* __restrict__ cs_ws,
            u16* __restrict__ posret, u16* __restrict__ xcat, u16* __restrict__ combined)
{
    int blk = blockIdx.x;
    int nc = blk & 15, dt = (blk >> 4) & 7, b = blk >> 7;
    int t = threadIdx.x; int dl = t & 63, lg = t >> 6;   // lg 0..7
    int d = dt * 64 + dl;
    float ms = fabsf(msc[0]);
    int l0 = nc * 128 + lg * 16;
    float sm = 0.f, swc = 0.f, sws = 0.f, sx = 0.f;
    for (int i = 0; i < 16; i++) {
        size_t r = (size_t)(b * L_ + l0 + i);
        float ph = phi[r * 512 + d];
        float mg = sigm(b2f(out1[r * 2560 + 1536 + d])) * ms;
        float wv = mg * b2f(out1[r * 2560 + 1024 + d]);
        float s = __sinf(ph), c = __cosf(ph);
        sm += mg; swc += wv * c; sws += wv * s; sx += x[r * 512 + d];
    }
    __shared__ float sh[4][8][64];
    sh[0][lg][dl] = sm; sh[1][lg][dl] = swc; sh[2][lg][dl] = sws; sh[3][lg][dl] = sx;
    __syncthreads();
    float cm = 0.f, cwc = 0.f, cws = 0.f, cx = 0.f;
    for (int p = 0; p < nc; p++) {
        size_t o = ((size_t)(b * 16 + p)) * 512 + d;
        cm += cs_m[o]; cwc += cs_wc[o]; cws += cs_ws[o]; cx += cs_x[o];
    }
    for (int g = 0; g < lg; g++) {
        cm += sh[0][g][dl]; cwc += sh[1][g][dl]; cws += sh[2][g][dl]; cx += sh[3][g][dl];
    }
    const float invsqD = 0.044194173824159216f;  // 1/sqrt(512)
    for (int i = 0; i < 16; i++) {
        int l = l0 + i;
        size_t r = (size_t)(b * L_ + l);
        float ph = phi[r * 512 + d];
        float mg = sigm(b2f(out1[r * 2560 + 1536 + d])) * ms;
        float wv = mg * b2f(out1[r * 2560 + 1024 + d]);
        float xv = x[r * 512 + d];
        float s = __sinf(ph), c = __cosf(ph);
        cm += mg; cwc += wv * c; cws += wv * s; cx += xv;
        float smag = sqrtf(cm + 1e-8f);
        float m1c = cwc / smag, m1s = cws / smag;
        float phq = ph + b2f(out1[r * 2560 + 2048 + d]);
        float sq = __sinf(phq), cq = __cosf(phq);
        float pr = (m1c * cq + m1s * sq) * invsqD;
        posret[r * 512 + d] = f2b(pr);
        xcat[r * 1024 + 512 + d] = f2b(cx / (float)(l + 1));
        combined[r * 2560 + 1536 + d] = f2b(xv * c);
        combined[r * 2560 + 2048 + d] = f2b(xv * s);
    }
}

// KV chunk-state sums + materialize sincos(storage_phase).
// Grid B*NC_, block 64: lane t covers p=t,p+64.
__global__ __launch_bounds__(64)
void kv_chunk(const float* __restrict__ sppre, const float* __restrict__ kesgo,
              float* __restrict__ spc, float* __restrict__ sps,
              float* __restrict__ csum)
{
    int blk = blockIdx.x; int nc = blk & (NC_ - 1), b = blk >> 7;
    int t = threadIdx.x;
    float Sc[2][8] = {}, Ss[2][8] = {};
    for (int i = 0; i < CH_; i++) {
        size_t r = (size_t)(b * L_ + nc * CH_ + i);
        float sgate = sigm(kesgo[r * 144 + 136]);
        float g[8];
#pragma unroll
        for (int v = 0; v < 8; v++) g[v] = kesgo[r * 144 + 128 + v] * sgate;
#pragma unroll
        for (int j = 0; j < 2; j++) {
            int p = t + j * 64;
            float sp = tanh_fast(sppre[r * 128 + p]) * PI_F;
            float s = __sinf(sp), c = __cosf(sp);
            spc[r * 128 + p] = c; sps[r * 128 + p] = s;
#pragma unroll
            for (int v = 0; v < 8; v++) { Sc[j][v] += c * g[v]; Ss[j][v] += s * g[v]; }
        }
    }
    size_t base = (size_t)blk * 2048;
#pragma unroll
    for (int j = 0; j < 2; j++)
#pragma unroll
        for (int v = 0; v < 8; v++) {
            csum[base + (t + j * 64) * 8 + v]        = Sc[j][v];
            csum[base + 1024 + (t + j * 64) * 8 + v] = Ss[j][v];
        }
}

// exclusive scan of chunk states over nc
__global__ __launch_bounds__(256)
void kv_scan(const float* __restrict__ cin, float* __restrict__ cex)
{
    int t = blockIdx.x * 256 + threadIdx.x;   // (b, cs, pv)
    int pv = t & 1023; int cs = (t >> 10) & 1; int b = t >> 11;
    float run = 0.f;
    for (int nc = 0; nc < NC_; nc++) {
        size_t o = ((size_t)(b * NC_ + nc)) * 2048 + cs * 1024 + pv;
        cex[o] = run; run += cin[o];
    }
}

// KV retrieve + fused kv_out linear -> combined cols [1024,1536)
__global__ __launch_bounds__(64)
void kv_retrieve(const float* __restrict__ spc, const float* __restrict__ sps,
                 const float* __restrict__ kesgo,
                 const float* __restrict__ gni, const float* __restrict__ cex,
                 const float* __restrict__ kvo_w, const float* __restrict__ kvo_b,
                 u16* __restrict__ combined)
{
    int blk = blockIdx.x; int nc = blk & (NC_ - 1), b = blk >> 7;
    int t = threadIdx.x;
    const int nb = t * 8;                 // this lane's 8 output cols
    float wr[8][8], br[8];
#pragma unroll
    for (int n = 0; n < 8; n++) {
        *(float4*)&wr[n][0] = *(const float4*)&kvo_w[(nb + n) * 8];
        *(float4*)&wr[n][4] = *(const float4*)&kvo_w[(nb + n) * 8 + 4];
        br[n] = kvo_b[nb + n];
    }
    float Sc[2][8], Ss[2][8];
    size_t base = (size_t)blk * 2048;
#pragma unroll
    for (int j = 0; j < 2; j++)
#pragma unroll
        for (int v = 0; v < 8; v++) {
            Sc[j][v] = cex[base + (t + j * 64) * 8 + v];
            Ss[j][v] = cex[base + 1024 + (t + j * 64) * 8 + v];
        }
    for (int i = 0; i < CH_; i++) {
        size_t r = (size_t)(b * L_ + nc * CH_ + i);
        float sgate = sigm(kesgo[r * 144 + 136]);
        float g[8];
#pragma unroll
        for (int v = 0; v < 8; v++) g[v] = kesgo[r * 144 + 128 + v] * sgate;
        float part[8];
#pragma unroll
        for (int v = 0; v < 8; v++) part[v] = 0.f;
#pragma unroll
        for (int j = 0; j < 2; j++) {
            int p = t + j * 64;
            float c = spc[r * 128 + p], s = sps[r * 128 + p];
#pragma unroll
            for (int v = 0; v < 8; v++) { Sc[j][v] += c * g[v]; Ss[j][v] += s * g[v]; }
            float qp = tanh_fast(kesgo[r * 144 + p]) * PI_F;
            float sq = __sinf(qp), cq = __cosf(qp);
#pragma unroll
            for (int v = 0; v < 8; v++) part[v] += cq * Sc[j][v] + sq * Ss[j][v];
        }
#pragma unroll
        for (int ofs = 1; ofs < 64; ofs <<= 1)
#pragma unroll
            for (int v = 0; v < 8; v++) part[v] += __shfl_xor(part[v], ofs, 64);
        float scale = gni[r] * 0.08838834764831845f;   // 1/sqrt(128)
        float pv[8];
#pragma unroll
        for (int v = 0; v < 8; v++) pv[v] = part[v] * scale;
        u16 outv[8];
#pragma unroll
        for (int n = 0; n < 8; n++) {
            float a = br[n];
#pragma unroll
            for (int v = 0; v < 8; v++) a += pv[v] * wr[n][v];
            outv[n] = f2b(a);
        }
        *(uint4*)&combined[r * 2560 + 1024 + nb] = *(const uint4*)outv;
    }
}

// layernorm over 2560, in place on bf16 combined.  Block 320 (5 waves), b128 I/O.
__global__ __launch_bounds__(320)
void ln_rows(u16* __restrict__ combined, const float* __restrict__ g, const float* __restrict__ bb)
{
    size_t m = blockIdx.x; int t = threadIdx.x;   // 0..319, one oct each
    u16 vv[8];
    *(uint4*)vv = *(const uint4*)&combined[m * 2560 + t * 8];
    float f[8]; float s = 0.f, s2 = 0.f;
#pragma unroll
    for (int k = 0; k < 8; k++) { f[k] = b2f(vv[k]); s += f[k]; s2 += f[k] * f[k]; }
#pragma unroll
    for (int ofs = 1; ofs < 64; ofs <<= 1) {
        s  += __shfl_xor(s, ofs, 64);
        s2 += __shfl_xor(s2, ofs, 64);
    }
    __shared__ float shs[5], shs2[5];
    int wv = t >> 6;
    if ((t & 63) == 0) { shs[wv] = s; shs2[wv] = s2; }
    __syncthreads();
    float S = 0.f, S2 = 0.f;
#pragma unroll
    for (int i = 0; i < 5; i++) { S += shs[i]; S2 += shs2[i]; }
    float mean = S * (1.0f / 2560.0f);
    float var  = S2 * (1.0f / 2560.0f) - mean * mean;
    float rstd = rsqrtf(var + 1e-5f);
#pragma unroll
    for (int k = 0; k < 8; k++) {
        int c = t * 8 + k;
        vv[k] = f2b((f[k] - mean) * rstd * g[c] + bb[c]);
    }
    *(uint4*)&combined[m * 2560 + t * 8] = *(const uint4*)vv;
}

// ---------------------------------------------------------------------------
extern "C" void kernel_launch(void* const* d_in, const int* in_sizes, int n_in,
                              void* d_out, int out_size, void* d_ws, size_t ws_size,
                              hipStream_t stream)
{
    const float* x     = (const float*)d_in[0];
    const float* lc_w  = (const float*)d_in[1];
    const float* lc_b  = (const float*)d_in[2];
    const float* cg_w  = (const float*)d_in[3];
    const float* cg_b  = (const float*)d_in[4];
    const float* cp_w  = (const float*)d_in[5];
    const float* cp_b  = (const float*)d_in[6];
    const float* tw_w  = (const float*)d_in[7];
    const float* tw_b  = (const float*)d_in[8];
    const float* omega_scale = (const float*)d_in[9];
    const float* pi0_w = (const float*)d_in[10];
    const float* pi0_b = (const float*)d_in[11];
    const float* pi2_w = (const float*)d_in[12];
    const float* pi2_b = (const float*)d_in[13];
    const float* m1v_w = (const float*)d_in[14];
    const float* m1v_b = (const float*)d_in[15];
    const float* m1o_w = (const float*)d_in[16];
    const float* m1o_b = (const float*)d_in[17];
    const float* mag_w = (const float*)d_in[18];
    const float* mag_b = (const float*)d_in[19];
    const float* mag_scale = (const float*)d_in[20];
    const float* qo_w  = (const float*)d_in[21];
    const float* qo_b  = (const float*)d_in[22];
    const float* ke_w  = (const float*)d_in[23];
    const float* ke_b  = (const float*)d_in[24];
    const float* ve_w  = (const float*)d_in[25];
    const float* ve_b  = (const float*)d_in[26];
    const float* sk0_w = (const float*)d_in[27];
    const float* sk0_b = (const float*)d_in[28];
    const float* sk2_w = (const float*)d_in[29];
    const float* sk2_b = (const float*)d_in[30];
    const float* sg_w  = (const float*)d_in[31];
    const float* sg_b  = (const float*)d_in[32];
    const float* kvo_w = (const float*)d_in[33];
    const float* kvo_b = (const float*)d_in[34];
    const float* ln_g  = (const float*)d_in[35];
    const float* ln_b  = (const float*)d_in[36];
    const float* o1_w  = (const float*)d_in[37];
    const float* o1_b  = (const float*)d_in[38];
    const float* o2_w  = (const float*)d_in[39];
    const float* o2_b  = (const float*)d_in[40];
    float* out = (float*)d_out;

    char* base = (char*)d_ws;
    size_t off = 0;
    auto alloc = [&](size_t bytes) -> void* {
        void* p = base + off;
        off += (bytes + 255) & ~(size_t)255;
        return p;
    };

    u16*   wcat1  = (u16*)  alloc((size_t)2560 * 512 * 2);
    float* bcat1  = (float*)alloc(2560 * 4);
    u16*   kesgw  = (u16*)  alloc((size_t)256 * 512 * 2);
    float* kesgb  = (float*)alloc(256 * 4);
    u16*   pi2w   = (u16*)  alloc((size_t)512 * 512 * 2);
    u16*   cpw    = (u16*)  alloc((size_t)512 * 512 * 2);
    u16*   sk0w   = (u16*)  alloc((size_t)512 * 1024 * 2);
    u16*   sk2w   = (u16*)  alloc((size_t)128 * 512 * 2);
    u16*   m1ow   = (u16*)  alloc((size_t)512 * 512 * 2);
    u16*   o1w    = (u16*)  alloc((size_t)1024 * 2560 * 2);
    u16*   o2w    = (u16*)  alloc((size_t)512 * 1024 * 2);
    // big transient buffers
    u16*   xcat   = (u16*)  alloc((size_t)BL * 1024 * 2);       // 16.8 MB
    u16*   out1   = (u16*)  alloc((size_t)BL * 2560 * 2);       // 41.9 MB
    u16*   phib   = (u16*)  alloc((size_t)BL * 512 * 2);        // 8.4 MB (bf16)
    float* phi    = (float*)alloc((size_t)BL * 512 * 4);        // 16.8 MB
    float* kesgo  = (float*)alloc((size_t)BL * 144 * 4);
    u16*   convg  = (u16*)  alloc((size_t)BL * 512 * 2);
    float* sppre  = (float*)alloc((size_t)BL * 128 * 4);
    u16*   combined = (u16*)alloc((size_t)BL * 2560 * 2);
    float* cs_o   = (float*)alloc((size_t)4 * 16 * 512 * 4);
    float* cs_x   = (float*)alloc((size_t)4 * 16 * 512 * 4);
    float* cs_m   = (float*)alloc((size_t)4 * 16 * 512 * 4);
    float* cs_wc  = (float*)alloc((size_t)4 * 16 * 512 * 4);
    float* cs_ws  = (float*)alloc((size_t)4 * 16 * 512 * 4);
    float* gni    = (float*)alloc((size_t)BL * 4);
    // aliases onto dead buffers (liveness):
    u16*   posret = convg;                 // convg dead after mega1
    u16*   sk0g   = out1;                  // out1 dead after scan_e
    float* spc    = phi;                   // phi dead after scan_e (4.2 MB)
    float* sps    = phi + (size_t)BL * 128;
    float* kvcs   = (float*)phib;          // phib dead after scan_c (4.2 MB)
    float* kvex   = (float*)phib + (size_t)B_ * NC_ * 2048;
    u16*   o1g    = xcat;                  // xcat dead after mega2
    (void)ws_size; (void)in_sizes; (void)n_in; (void)out_size;

    const size_t SMEM = 36864;             // 3-slot ring, 12KB/slot

    // 1. weight prep
    prep_weights<<<23307, 256, 0, stream>>>(
        tw_w, pi0_w, m1v_w, mag_w, qo_w, ke_w, ve_w, sg_w,
        pi2_w, cp_w, sk0_w, sk2_w, m1o_w, o1_w, o2_w,
        tw_b, pi0_b, m1v_b, mag_b, qo_b, ke_b, ve_b, sg_b,
        wcat1, bcat1, kesgw, kesgb, pi2w, cpw, sk0w, sk2w, m1ow, o1w, o2w);
    // 2. conv branch input + cast x into xcat
    conv_gate<<<16384, 256, 0, stream>>>(x, lc_w, lc_b, cg_w, cg_b, convg, xcat);
    // 3. mega1: pass1 [omega | gelu(pi0) | v1 | mag | qoff] + ke/ve/sg + conv proj
    mega1<<<dim3(64, 51), 256, SMEM, stream>>>(xcat, convg, wcat1, bcat1,
                                               kesgw, kesgb, cpw, cp_b,
                                               out1, kesgo, combined);
    // 4. stage2: pi2 -> phib (bf16) + scan_a + gate scan, one dispatch
    stage2<<<1025, 256, SMEM, stream>>>(out1, pi2w, pi2_b, phib,
                                        x, omega_scale, mag_scale,
                                        cs_o, cs_x, cs_m, kesgo, gni);
    // 5-6. chunked scans (512 threads: 16 rows/thread, 16 waves/CU)
    scan_c<<<512, 512, 0, stream>>>(out1, phib, omega_scale, mag_scale, cs_o,
                                    phi, cs_wc, cs_ws);
    scan_e<<<512, 512, 0, stream>>>(out1, phi, x, mag_scale, cs_m, cs_x, cs_wc, cs_ws,
                                    posret, xcat, combined);
    // 7. mega2: pos_out + sk0(gelu)
    mega2<<<dim3(64, 16), 256, SMEM, stream>>>(posret, xcat, m1ow, m1o_b,
                                               sk0w, sk0_b, combined, sk0g);
    // 8. sk2 -> storage phase pre-tanh (split-K=4, atomic f32)
    hipMemsetAsync(sppre, 0, (size_t)BL * 128 * 4, stream);
    gemm256<EPI_ATOMIC><<<dim3(64, 2, 4), 256, SMEM, stream>>>(sk0g, 512, sk2w, 512, sk2_b,
                                                               sppre, 128, 128, 128, nullptr);
    // 9-11. KV memory (chunk=16, 128 chunks/batch)
    kv_chunk<<<4 * NC_, 64, 0, stream>>>(sppre, kesgo, spc, sps, kvcs);
    kv_scan<<<32, 256, 0, stream>>>(kvcs, kvex);
    kv_retrieve<<<4 * NC_, 64, 0, stream>>>(spc, sps, kesgo, gni, kvex, kvo_w, kvo_b, combined);
    // 12. layernorm in place
    ln_rows<<<8192, 320, 0, stream>>>(combined, ln_g, ln_b);
    // 13. o1 + gelu -> o1g
    gemm256<EPI_GELU_BF16><<<dim3(64, 16), 256, SMEM, stream>>>(combined, 2560, o1w, 2560, o1_b,
                                                                o1g, 1024, 1024, 2560, nullptr);
    // 14. o2 + residual -> out
    gemm256<EPI_RESID_F32><<<dim3(64, 8), 256, SMEM, stream>>>(o1g, 1024, o2w, 1024, o2_b,
                                                               out, 512, 512, 1024, x);
}

// Round 10
// 505.489 us; speedup vs baseline: 1.1447x; 1.1447x over previous
//
#include <hip/hip_runtime.h>
#include <cstdint>

typedef unsigned short u16;
typedef short short8 __attribute__((ext_vector_type(8)));
typedef float floatx4 __attribute__((ext_vector_type(4)));

#define B_ 4
#define L_ 2048
#define D_ 512
#define P_ 128
#define V_ 8
#define BL (B_ * L_)        // 8192
#define NC_ 256             // KV chunks per batch (R10: was 128)
#define CH_ 8               // KV chunk length (R10: was 16 — halves serial chain)
#define PI_F 3.14159265358979323846f

__device__ inline u16 f2b(float f) {
    unsigned u = __float_as_uint(f);
    unsigned r = u + 0x7FFFu + ((u >> 16) & 1u);
    return (u16)(r >> 16);
}
__device__ inline float b2f(u16 h) {
    return __uint_as_float(((unsigned)h) << 16);
}
__device__ inline float gelu_f(float v) {
    return 0.5f * v * (1.0f + erff(v * 0.70710678118654752f));
}
__device__ inline float sigm(float v) {
    return 1.0f / (1.0f + __expf(-v));
}
__device__ inline float tanh_fast(float v) {
    return 1.0f - 2.0f / (1.0f + __expf(2.0f * v));
}

// async global->LDS, 16B per lane. LDS dest is wave-uniform base + lane*16.
__device__ inline void async16(const u16* g, u16* l) {
    __builtin_amdgcn_global_load_lds(
        (const __attribute__((address_space(1))) unsigned int*)g,
        (__attribute__((address_space(3))) unsigned int*)l, 16, 0, 0);
}

extern __shared__ u16 smem_dyn[];   // 49152 B: 3-slot ring of (A 8KB + B 8KB)

// ---------------------------------------------------------------------------
// 128x128-tile bf16 MFMA GEMM body, BK=32, COMPILE-TIME epilogue.
// R10 = R5/R8 GEMM verbatim (best measured; R9's BN=64 raised FETCH +55% and
// regressed -> reverted).  8 waves (512 thr), 2x4 wave grid, 64x32 output
// per wave, acc[4][2] -> 16 waves/CU at 2 blocks/CU.
//   * T2 XOR-swizzle (measured 0 bank conflicts): LDS[row][cg] holds
//     global[row][cg ^ ((row>>1)&3)]; linear LDS dest + pre-swizzled global
//     source + swizzled read.
//   * Fragment double-buffer: frag t+1 ds_read during MFMA t.
//   * 3-slot ring, stage(t+3) after barrier, global prefetch depth 2 K-steps.
//   * Per-iter: lgkm(0)[frag t ready] -> vmcnt(2)[stage t+1 landed; steady
//     outstanding = stages {t+1,t+2} = 4 loads] -> barrier -> stage(t+3)
//     -> ds_read frag t+1 || 8xMFMA t.  Prologue outstanding 6 -> vmcnt(4).
//     WAR: own-wave frag-t reads drained by pre-barrier lgkm(0); cross-wave
//     by the barrier.  RAW: per-wave vmcnt pre-barrier + barrier.
// 512 threads = 8 waves.  C[m,n] = epi( sum_k A[m,k]*W[n,k] + bias[n] ).
// Requires nsteps = K/32 EVEN and >= 4 (call sites: K in {128,512,1024,2560}).
// ---------------------------------------------------------------------------
enum { EPI_F32 = 0, EPI_BF16 = 1, EPI_GELU_BF16 = 2, EPI_RESID_F32 = 3,
       EPI_PASS1 = 4, EPI_ATOMIC = 5 };

template <int EPI>
__device__ __forceinline__ void gemm_body(
    const u16* __restrict__ A, int lda,
    const u16* __restrict__ W, int ldw,
    const float* __restrict__ bias,
    void* __restrict__ Cout, int ldc, int N, int K,
    const float* __restrict__ resid, int mt, int nt)
{
    const int tid  = threadIdx.x;
    const int lane = tid & 63;
    const int wid  = tid >> 6;               // 0..7
    const int wm   = wid & 1, wn = wid >> 1; // 2 x 4 wave grid
    const int l16  = lane & 15, quad = lane >> 4;
    const int rswz = (l16 >> 1) & 3;          // read-side cg XOR ((row>>1)&3)

    floatx4 acc[4][2] = {};

    const u16* Ab = A + (size_t)(mt * 128) * lda;
    const u16* Wb = W + (size_t)(nt * 128) * ldw;

    const int srow = lane >> 2;
    // source column pre-swizzled so linear LDS write lands swizzled data
    const int scol = ((lane & 3) ^ ((srow >> 1) & 3)) * 8;
    // wave w stages A rows [16w,16w+16) and B rows [16w,16w+16) of the tile
    const u16* ga0 = Ab + (size_t)(wid * 16 + srow) * lda + scol;
    const u16* gb0 = Wb + (size_t)(wid * 16 + srow) * ldw + scol;
    const int lW = wid * 512;                 // wave-uniform LDS chunk (u16)

    const int nsteps = K >> 5;

    auto stage = [&](int t, int s) {
        u16* base = smem_dyn + s * 8192;      // 8192 u16 = 16KB per slot
        const int ko = t * 32;
        async16(ga0 + ko, base + lW);
        async16(gb0 + ko, base + 4096 + lW);
    };

    auto readfrag = [&](int slot, short8 (&a)[4], short8 (&b)[2]) {
        const u16* As = smem_dyn + slot * 8192;
        const u16* Bs = As + 4096;
#pragma unroll
        for (int i = 0; i < 4; i++)
            a[i] = *(const short8*)(&As[(wm * 64 + i * 16 + l16) * 32 + (quad ^ rswz) * 8]);
#pragma unroll
        for (int j = 0; j < 2; j++)
            b[j] = *(const short8*)(&Bs[(wn * 32 + j * 16 + l16) * 32 + (quad ^ rswz) * 8]);
    };

    auto mfma8 = [&](short8 (&a)[4], short8 (&b)[2]) {
        __builtin_amdgcn_s_setprio(1);
#pragma unroll
        for (int i = 0; i < 4; i++)
#pragma unroll
            for (int j = 0; j < 2; j++)
                acc[i][j] = __builtin_amdgcn_mfma_f32_16x16x32_bf16(a[i], b[j], acc[i][j], 0, 0, 0);
        __builtin_amdgcn_s_setprio(0);
    };

    // prologue: fill the ring (2 loads/stage -> 6 outstanding), confirm stage 0
    stage(0, 0);
    if (nsteps > 1) stage(1, 1);
    if (nsteps > 2) stage(2, 2);
    if (nsteps > 2)      asm volatile("s_waitcnt vmcnt(4)" ::: "memory");
    else if (nsteps > 1) asm volatile("s_waitcnt vmcnt(2)" ::: "memory");
    else                 asm volatile("s_waitcnt vmcnt(0)" ::: "memory");
    __builtin_amdgcn_s_barrier();
    asm volatile("" ::: "memory");

    short8 aE[4], bE[2], aO[4], bO[2];
    readfrag(0, aE, bE);

    for (int t = 0; t < nsteps; t += 2) {
        // ---- even iter: consume set E, prefetch set O ----
        asm volatile("s_waitcnt lgkmcnt(0)" ::: "memory");   // frag t in regs
        if (t + 2 < nsteps)      asm volatile("s_waitcnt vmcnt(2)" ::: "memory");
        else if (t + 1 < nsteps) asm volatile("s_waitcnt vmcnt(0)" ::: "memory");
        __builtin_amdgcn_s_barrier();
        asm volatile("" ::: "memory");
        if (t + 3 < nsteps) stage(t + 3, t % 3);
        if (t + 1 < nsteps) readfrag((t + 1) % 3, aO, bO);
        mfma8(aE, bE);
        // ---- odd iter: consume set O, prefetch set E ----
        const int t1 = t + 1;                                 // < nsteps (even nsteps)
        asm volatile("s_waitcnt lgkmcnt(0)" ::: "memory");
        if (t1 + 2 < nsteps)      asm volatile("s_waitcnt vmcnt(2)" ::: "memory");
        else if (t1 + 1 < nsteps) asm volatile("s_waitcnt vmcnt(0)" ::: "memory");
        __builtin_amdgcn_s_barrier();
        asm volatile("" ::: "memory");
        if (t1 + 3 < nsteps) stage(t1 + 3, t1 % 3);
        if (t1 + 1 < nsteps) readfrag((t1 + 1) % 3, aE, bE);
        mfma8(aO, bO);
    }

#pragma unroll
    for (int i = 0; i < 4; i++) {
#pragma unroll
        for (int j = 0; j < 2; j++) {
#pragma unroll
            for (int r = 0; r < 4; r++) {
                int grow = mt * 128 + wm * 64 + i * 16 + quad * 4 + r;
                int gcol = nt * 128 + wn * 32 + j * 16 + l16;
                if (gcol < N) {
                    float v = acc[i][j][r] + (bias ? bias[gcol] : 0.0f);
                    size_t off = (size_t)grow * ldc + gcol;
                    if (EPI == EPI_F32)            ((float*)Cout)[off] = v;
                    else if (EPI == EPI_BF16)      ((u16*)Cout)[off] = f2b(v);
                    else if (EPI == EPI_GELU_BF16) ((u16*)Cout)[off] = f2b(gelu_f(v));
                    else if (EPI == EPI_PASS1) {
                        float vv = (gcol >= 512 && gcol < 1024) ? gelu_f(v) : v;
                        ((u16*)Cout)[off] = f2b(vv);
                    }
                    else if (EPI == EPI_RESID_F32) ((float*)Cout)[off] = v + resid[off];
                    else                           atomicAdd(&((float*)Cout)[off], v);
                }
            }
        }
    }
}

// generic GEMM; grid.z = split-K slice (A,W advance by kz*K along k; bias slice 0)
template <int EPI>
__global__ __launch_bounds__(512)
void gemm256(const u16* __restrict__ A, int lda,
             const u16* __restrict__ W, int ldw,
             const float* __restrict__ bias,
             void* __restrict__ C, int ldc, int N, int K,
             const float* __restrict__ resid)
{
    int kz = blockIdx.z;
    gemm_body<EPI>(A + (size_t)kz * K, lda, W + (size_t)kz * K, ldw,
                   kz == 0 ? bias : nullptr, C, ldc, N, K, resid,
                   blockIdx.x, blockIdx.y);
}

// pass1 (N=2560,y 0..19) + ke/ve/sg (N=144,y 20..21) + conv proj (y 22..25)
__global__ __launch_bounds__(512)
void mega1(const u16* __restrict__ xcat, const u16* __restrict__ convg,
           const u16* __restrict__ wcat1, const float* __restrict__ bcat1,
           const u16* __restrict__ kesgw, const float* __restrict__ kesgb,
           const u16* __restrict__ cpw, const float* __restrict__ cp_b,
           u16* __restrict__ out1, float* __restrict__ kesgo, u16* __restrict__ combined)
{
    int y = blockIdx.y, mt = blockIdx.x;
    if (y < 20)
        gemm_body<EPI_PASS1>(xcat, 1024, wcat1, 512, bcat1, out1, 2560, 2560, 512, nullptr, mt, y);
    else if (y < 22)
        gemm_body<EPI_F32>(xcat, 1024, kesgw, 512, kesgb, kesgo, 144, 144, 512, nullptr, mt, y - 20);
    else
        gemm_body<EPI_BF16>(convg, 512, cpw, 512, cp_b, combined, 2560, 512, 512, nullptr, mt, y - 22);
}

// pos_out (y 0..3) + sk0 (y 4..7)
__global__ __launch_bounds__(512)
void mega2(const u16* __restrict__ posret, const u16* __restrict__ xcat,
           const u16* __restrict__ m1ow, const float* __restrict__ m1o_b,
           const u16* __restrict__ sk0w, const float* __restrict__ sk0_b,
           u16* __restrict__ combined, u16* __restrict__ sk0g)
{
    int y = blockIdx.y, mt = blockIdx.x;
    if (y < 4)
        gemm_body<EPI_BF16>(posret, 512, m1ow, 512, m1o_b, combined + 512, 2560, 512, 512, nullptr, mt, y);
    else
        gemm_body<EPI_GELU_BF16>(xcat, 1024, sk0w, 1024, sk0_b, sk0g, 512, 512, 1024, nullptr, mt, y - 4);
}

// ---------------------------------------------------------------------------
// Weight prep: cast fp32 weights -> bf16, build concatenations + pads.
// ---------------------------------------------------------------------------
__global__ __launch_bounds__(256)
void prep_weights(const float* tw, const float* pi0, const float* m1v, const float* mag, const float* qo,
                  const float* ke, const float* ve, const float* sg,
                  const float* pi2, const float* cp, const float* sk0, const float* sk2,
                  const float* m1o, const float* o1, const float* o2,
                  const float* tw_b, const float* pi0_b, const float* m1v_b, const float* mag_b, const float* qo_b,
                  const float* ke_b, const float* ve_b, const float* sg_b,
                  u16* wcat1, float* bcat1, u16* kesgw, float* kesgb,
                  u16* pi2w, u16* cpw, u16* sk0w, u16* sk2w, u16* m1ow, u16* o1w, u16* o2w)
{
    int idx = blockIdx.x * 256 + threadIdx.x;
    const int n0 = 2560 * 512;
    const int n1 = n0 + 256 * 512;
    const int n2 = n1 + 512 * 512;
    const int n3 = n2 + 512 * 512;
    const int n4 = n3 + 512 * 1024;
    const int n5 = n4 + 128 * 512;
    const int n6 = n5 + 512 * 512;
    const int n7 = n6 + 1024 * 2560;
    const int n8 = n7 + 512 * 1024;
    const int n9 = n8 + 2560;
    const int n10 = n9 + 256;
    if (idx < n0) {
        int r = idx >> 9, k = idx & 511;
        const float* s = (r < 512) ? tw : (r < 1024) ? pi0 : (r < 1536) ? m1v : (r < 2048) ? mag : qo;
        wcat1[idx] = f2b(s[(r & 511) * 512 + k]);
    } else if (idx < n1) {
        int i = idx - n0; int r = i >> 9, k = i & 511;
        float v;
        if (r < 128)      v = ke[r * 512 + k];
        else if (r < 136) v = ve[(r - 128) * 512 + k];
        else if (r == 136) v = sg[k];
        else               v = 0.0f;
        kesgw[i] = f2b(v);
    }
    else if (idx < n2) { int i = idx - n1; pi2w[i] = f2b(pi2[i]); }
    else if (idx < n3) { int i = idx - n2; cpw[i]  = f2b(cp[i]); }
    else if (idx < n4) { int i = idx - n3; sk0w[i] = f2b(sk0[i]); }
    else if (idx < n5) { int i = idx - n4; sk2w[i] = f2b(sk2[i]); }
    else if (idx < n6) { int i = idx - n5; m1ow[i] = f2b(m1o[i]); }
    else if (idx < n7) { int i = idx - n6; o1w[i]  = f2b(o1[i]); }
    else if (idx < n8) { int i = idx - n7; o2w[i]  = f2b(o2[i]); }
    else if (idx < n9) {
        int i = idx - n8;
        const float* s = (i < 512) ? tw_b : (i < 1024) ? pi0_b : (i < 1536) ? m1v_b : (i < 2048) ? mag_b : qo_b;
        bcat1[i] = s[i & 511];
    } else if (idx < n10) {
        int i = idx - n9;
        kesgb[i] = (i < 128) ? ke_b[i] : (i < 136) ? ve_b[i - 128] : (i == 136) ? sg_b[0] : 0.0f;
    }
}

// depthwise causal conv (K=4) gated branch + cast x into xcat cols [0,512)
__global__ __launch_bounds__(256)
void conv_gate(const float* __restrict__ x,
               const float* __restrict__ lcw, const float* __restrict__ lcb,
               const float* __restrict__ cgw, const float* __restrict__ cgb,
               u16* __restrict__ out, u16* __restrict__ xcat)
{
    int idx = blockIdx.x * 256 + threadIdx.x;   // over BL*512
    int d = idx & 511; int bl = idx >> 9;
    int l = bl & (L_ - 1); int b = bl >> 11;
    float a0 = 0.f, a1 = 0.f, xv3 = 0.f;
#pragma unroll
    for (int k = 0; k < 4; k++) {
        int ls = l - 3 + k;
        if (ls >= 0) {
            float xv = x[((size_t)(b * L_ + ls)) * 512 + d];
            if (k == 3) xv3 = xv;
            a0 += xv * lcw[d * 4 + k];
            a1 += xv * cgw[d * 4 + k];
        }
    }
    a0 += lcb[d];
    a1 = sigm(a1 + cgb[d]);
    out[idx] = f2b(a0 * a1);
    xcat[(size_t)bl * 1024 + d] = f2b(xv3);
}

// ---------------------------------------------------------------------------
// scan_a body (512-thread version): per-chunk sums of omega/mag/x.
// blk = b(4) x dt(8) x nc(16).  8 groups of 64 lanes, 16 rows each.
// ---------------------------------------------------------------------------
__device__ __forceinline__ void scan_a_body(
    int blk, const u16* __restrict__ out1, const float* __restrict__ x,
    const float* __restrict__ oscale, const float* __restrict__ msc,
    float* __restrict__ cs_o, float* __restrict__ cs_x, float* __restrict__ cs_m)
{
    int nc = blk & 15, dt = (blk >> 4) & 7, b = blk >> 7;
    int t = threadIdx.x; int dl = t & 63, lg = t >> 6;   // lg 0..7
    int d = dt * 64 + dl;
    float os = fabsf(oscale[d]);
    float ms = fabsf(msc[0]);
    float so = 0.f, sx = 0.f, sm = 0.f;
    int l0 = nc * 128 + lg * 16;
    for (int i = 0; i < 16; i++) {
        size_t r = (size_t)(b * L_ + l0 + i);
        so += b2f(out1[r * 2560 + d]) * os;
        sm += sigm(b2f(out1[r * 2560 + 1536 + d])) * ms;
        sx += x[r * 512 + d];
    }
    __shared__ float sh[3][8][64];
    sh[0][lg][dl] = so; sh[1][lg][dl] = sx; sh[2][lg][dl] = sm;
    __syncthreads();
    if (t < 64) {
        float a = 0.f, xx = 0.f, m = 0.f;
        for (int g = 0; g < 8; g++) { a += sh[0][g][t]; xx += sh[1][g][t]; m += sh[2][g][t]; }
        size_t o = ((size_t)(b * 16 + nc)) * 512 + dt * 64 + t;
        cs_o[o] = a; cs_x[o] = xx; cs_m[o] = m;
    }
}

// store-gate scan: wave w handles batch w (waves 0..3 of the block; no barrier).
__device__ __forceinline__ void gate_body(const float* __restrict__ kesgo,
                                          float* __restrict__ gni)
{
    if (threadIdx.x >= 256) return;           // waves 4..7 idle (no barrier here)
    int b = threadIdx.x >> 6; int lane = threadIdx.x & 63;
    float v[32]; float s = 0.f;
#pragma unroll
    for (int i = 0; i < 32; i++) {
        int l = lane * 32 + i;
        v[i] = sigm(kesgo[((size_t)(b * L_ + l)) * 144 + 136]);
        s += v[i];
    }
    float sc = s;
#pragma unroll
    for (int ofs = 1; ofs < 64; ofs <<= 1) {
        float t = __shfl_up(sc, ofs, 64);
        if (lane >= ofs) sc += t;
    }
    float run = sc - s;   // exclusive prefix
#pragma unroll
    for (int i = 0; i < 32; i++) {
        run += v[i];
        gni[b * L_ + lane * 32 + i] = rsqrtf(fmaxf(run, 1.0f));
    }
}

// fused: pi2 GEMM (blocks 0..255) + scan_a (256..767) + gate scan (768)
__global__ __launch_bounds__(512)
void stage2(const u16* __restrict__ out1, const u16* __restrict__ pi2w,
            const float* __restrict__ pi2_b, u16* __restrict__ phib,
            const float* __restrict__ x, const float* __restrict__ oscale,
            const float* __restrict__ msc,
            float* __restrict__ cs_o, float* __restrict__ cs_x, float* __restrict__ cs_m,
            const float* __restrict__ kesgo, float* __restrict__ gni)
{
    int blk = blockIdx.x;
    if (blk < 256)
        gemm_body<EPI_BF16>(out1 + 512, 2560, pi2w, 512, pi2_b, phib, 512, 512, 512,
                            nullptr, blk & 63, blk >> 6);
    else if (blk < 768)
        scan_a_body(blk - 256, out1, x, oscale, msc, cs_o, cs_x, cs_m);
    else
        gate_body(kesgo, gni);
}

// scan_c (512 threads, 16 rows/thread — R8 latency-regime widening, kept).
__global__ __launch_bounds__(512)
void scan_c(const u16* __restrict__ out1, const u16* __restrict__ phib,
            const float* __restrict__ oscale, const float* __restrict__ msc,
            const float* __restrict__ cs_o,
            float* __restrict__ phi, float* __restrict__ cs_wc, float* __restrict__ cs_ws)
{
    int blk = blockIdx.x;
    int nc = blk & 15, dt = (blk >> 4) & 7, b = blk >> 7;
    int t = threadIdx.x; int dl = t & 63, lg = t >> 6;   // lg 0..7
    int d = dt * 64 + dl;
    float os = fabsf(oscale[d]);
    float ms = fabsf(msc[0]);
    int l0 = nc * 128 + lg * 16;
    float so = 0.f;
    for (int i = 0; i < 16; i++) {
        size_t r = (size_t)(b * L_ + l0 + i);
        so += b2f(out1[r * 2560 + d]) * os;
    }
    __shared__ float sh[8][64];
    __shared__ float shw[2][8][64];
    sh[lg][dl] = so;
    __syncthreads();
    float pre = 0.f;
    for (int p = 0; p < nc; p++) pre += cs_o[((size_t)(b * 16 + p)) * 512 + d];
    for (int g = 0; g < lg; g++) pre += sh[g][dl];
    float cum = pre, swc = 0.f, sws = 0.f;
    for (int i = 0; i < 16; i++) {
        size_t r = (size_t)(b * L_ + l0 + i);
        cum += b2f(out1[r * 2560 + d]) * os;
        float ph = b2f(phib[r * 512 + d]) + cum;
        phi[r * 512 + d] = ph;
        float mg = sigm(b2f(out1[r * 2560 + 1536 + d])) * ms;
        float wv = mg * b2f(out1[r * 2560 + 1024 + d]);
        float s = __sinf(ph), c = __cosf(ph);
        swc += wv * c; sws += wv * s;
    }
    shw[0][lg][dl] = swc; shw[1][lg][dl] = sws;
    __syncthreads();
    if (t < 64) {
        float a = 0.f, bb = 0.f;
        for (int g = 0; g < 8; g++) { a += shw[0][g][t]; bb += shw[1][g][t]; }
        size_t o = ((size_t)(b * 16 + nc)) * 512 + dt * 64 + t;
        cs_wc[o] = a; cs_ws[o] = bb;
    }
}

// scan_e (512 threads, 16 rows/thread — R8 widening, kept).
__global__ __launch_bounds__(512)
void scan_e(const u16* __restrict__ out1, const float* __restrict__ phi,
            const float* __restrict__ x, const float* __restrict__ msc,
            const float* __restrict__ cs_m, const float* __restrict__ cs_x,
            const float* __restrict__ cs_wc, const float* __restrict__ cs_ws,
            u16* __restrict__ posret, u16* __restrict__ xcat, u16* __restrict__ combined)
{
    int blk = blockIdx.x;
    int nc = blk & 15, dt = (blk >> 4) & 7, b = blk >> 7;
    int t = threadIdx.x; int dl = t & 63, lg = t >> 6;   // lg 0..7
    int d = dt * 64 + dl;
    float ms = fabsf(msc[0]);
    int l0 = nc * 128 + lg * 16;
    float sm = 0.f, swc = 0.f, sws = 0.f, sx = 0.f;
    for (int i = 0; i < 16; i++) {
        size_t r = (size_t)(b * L_ + l0 + i);
        float ph = phi[r * 512 + d];
        float mg = sigm(b2f(out1[r * 2560 + 1536 + d])) * ms;
        float wv = mg * b2f(out1[r * 2560 + 1024 + d]);
        float s = __sinf(ph), c = __cosf(ph);
        sm += mg; swc += wv * c; sws += wv * s; sx += x[r * 512 + d];
    }
    __shared__ float sh[4][8][64];
    sh[0][lg][dl] = sm; sh[1][lg][dl] = swc; sh[2][lg][dl] = sws; sh[3][lg][dl] = sx;
    __syncthreads();
    float cm = 0.f, cwc = 0.f, cws = 0.f, cx = 0.f;
    for (int p = 0; p < nc; p++) {
        size_t o = ((size_t)(b * 16 + p)) * 512 + d;
        cm += cs_m[o]; cwc += cs_wc[o]; cws += cs_ws[o]; cx += cs_x[o];
    }
    for (int g = 0; g < lg; g++) {
        cm += sh[0][g][dl]; cwc += sh[1][g][dl]; cws += sh[2][g][dl]; cx += sh[3][g][dl];
    }
    const float invsqD = 0.044194173824159216f;  // 1/sqrt(512)
    for (int i = 0; i < 16; i++) {
        int l = l0 + i;
        size_t r = (size_t)(b * L_ + l);
        float ph = phi[r * 512 + d];
        float mg = sigm(b2f(out1[r * 2560 + 1536 + d])) * ms;
        float wv = mg * b2f(out1[r * 2560 + 1024 + d]);
        float xv = x[r * 512 + d];
        float s = __sinf(ph), c = __cosf(ph);
        cm += mg; cwc += wv * c; cws += wv * s; cx += xv;
        float smag = sqrtf(cm + 1e-8f);
        float m1c = cwc / smag, m1s = cws / smag;
        float phq = ph + b2f(out1[r * 2560 + 2048 + d]);
        float sq = __sinf(phq), cq = __cosf(phq);
        float pr = (m1c * cq + m1s * sq) * invsqD;
        posret[r * 512 + d] = f2b(pr);
        xcat[r * 1024 + 512 + d] = f2b(cx / (float)(l + 1));
        combined[r * 2560 + 1536 + d] = f2b(xv * c);
        combined[r * 2560 + 2048 + d] = f2b(xv * s);
    }
}

// KV chunk-state sums + materialize sincos(storage_phase).
// R10: NC_=256, CH_=8 -> 1024 blocks (4 waves/CU, was 2) and half the
// serial per-block chain.  Latency-regime fix for a 64-thread kernel.
// Grid B*NC_, block 64: lane t covers p=t,p+64.
__global__ __launch_bounds__(64)
void kv_chunk(const float* __restrict__ sppre, const float* __restrict__ kesgo,
              float* __restrict__ spc, float* __restrict__ sps,
              float* __restrict__ csum)
{
    int blk = blockIdx.x; int nc = blk & (NC_ - 1), b = blk >> 8;
    int t = threadIdx.x;
    float Sc[2][8] = {}, Ss[2][8] = {};
    for (int i = 0; i < CH_; i++) {
        size_t r = (size_t)(b * L_ + nc * CH_ + i);
        float sgate = sigm(kesgo[r * 144 + 136]);
        float g[8];
#pragma unroll
        for (int v = 0; v < 8; v++) g[v] = kesgo[r * 144 + 128 + v] * sgate;
#pragma unroll
        for (int j = 0; j < 2; j++) {
            int p = t + j * 64;
            float sp = tanh_fast(sppre[r * 128 + p]) * PI_F;
            float s = __sinf(sp), c = __cosf(sp);
            spc[r * 128 + p] = c; sps[r * 128 + p] = s;
#pragma unroll
            for (int v = 0; v < 8; v++) { Sc[j][v] += c * g[v]; Ss[j][v] += s * g[v]; }
        }
    }
    size_t base = (size_t)blk * 2048;
#pragma unroll
    for (int j = 0; j < 2; j++)
#pragma unroll
        for (int v = 0; v < 8; v++) {
            csum[base + (t + j * 64) * 8 + v]        = Sc[j][v];
            csum[base + 1024 + (t + j * 64) * 8 + v] = Ss[j][v];
        }
}

// exclusive scan of chunk states over nc (NC_=256 iterations; loads are
// independent of the add chain -> pipelined fine).
__global__ __launch_bounds__(256)
void kv_scan(const float* __restrict__ cin, float* __restrict__ cex)
{
    int t = blockIdx.x * 256 + threadIdx.x;   // (b, cs, pv)
    int pv = t & 1023; int cs = (t >> 10) & 1; int b = t >> 11;
    float run = 0.f;
    for (int nc = 0; nc < NC_; nc++) {
        size_t o = ((size_t)(b * NC_ + nc)) * 2048 + cs * 1024 + pv;
        cex[o] = run; run += cin[o];
    }
}

// KV retrieve + fused kv_out linear -> combined cols [1024,1536)
// R10: 1024 blocks (4 waves/CU), CH_=8 serial rows per block.
__global__ __launch_bounds__(64)
void kv_retrieve(const float* __restrict__ spc, const float* __restrict__ sps,
                 const float* __restrict__ kesgo,
                 const float* __restrict__ gni, const float* __restrict__ cex,
                 const float* __restrict__ kvo_w, const float* __restrict__ kvo_b,
                 u16* __restrict__ combined)
{
    int blk = blockIdx.x; int nc = blk & (NC_ - 1), b = blk >> 8;
    int t = threadIdx.x;
    const int nb = t * 8;                 // this lane's 8 output cols
    float wr[8][8], br[8];
#pragma unroll
    for (int n = 0; n < 8; n++) {
        *(float4*)&wr[n][0] = *(const float4*)&kvo_w[(nb + n) * 8];
        *(float4*)&wr[n][4] = *(const float4*)&kvo_w[(nb + n) * 8 + 4];
        br[n] = kvo_b[nb + n];
    }
    float Sc[2][8], Ss[2][8];
    size_t base = (size_t)blk * 2048;
#pragma unroll
    for (int j = 0; j < 2; j++)
#pragma unroll
        for (int v = 0; v < 8; v++) {
            Sc[j][v] = cex[base + (t + j * 64) * 8 + v];
            Ss[j][v] = cex[base + 1024 + (t + j * 64) * 8 + v];
        }
    for (int i = 0; i < CH_; i++) {
        size_t r = (size_t)(b * L_ + nc * CH_ + i);
        float sgate = sigm(kesgo[r * 144 + 136]);
        float g[8];
#pragma unroll
        for (int v = 0; v < 8; v++) g[v] = kesgo[r * 144 + 128 + v] * sgate;
        float part[8];
#pragma unroll
        for (int v = 0; v < 8; v++) part[v] = 0.f;
#pragma unroll
        for (int j = 0; j < 2; j++) {
            int p = t + j * 64;
            float c = spc[r * 128 + p], s = sps[r * 128 + p];
#pragma unroll
            for (int v = 0; v < 8; v++) { Sc[j][v] += c * g[v]; Ss[j][v] += s * g[v]; }
            float qp = tanh_fast(kesgo[r * 144 + p]) * PI_F;
            float sq = __sinf(qp), cq = __cosf(qp);
#pragma unroll
            for (int v = 0; v < 8; v++) part[v] += cq * Sc[j][v] + sq * Ss[j][v];
        }
#pragma unroll
        for (int ofs = 1; ofs < 64; ofs <<= 1)
#pragma unroll
            for (int v = 0; v < 8; v++) part[v] += __shfl_xor(part[v], ofs, 64);
        float scale = gni[r] * 0.08838834764831845f;   // 1/sqrt(128)
        float pv[8];
#pragma unroll
        for (int v = 0; v < 8; v++) pv[v] = part[v] * scale;
        u16 outv[8];
#pragma unroll
        for (int n = 0; n < 8; n++) {
            float a = br[n];
#pragma unroll
            for (int v = 0; v < 8; v++) a += pv[v] * wr[n][v];
            outv[n] = f2b(a);
        }
        *(uint4*)&combined[r * 2560 + 1024 + nb] = *(const uint4*)outv;
    }
}

// layernorm over 2560, in place on bf16 combined.  Block 320 (5 waves), b128 I/O.
__global__ __launch_bounds__(320)
void ln_rows(u16* __restrict__ combined, const float* __restrict__ g, const float* __restrict__ bb)
{
    size_t m = blockIdx.x; int t = threadIdx.x;   // 0..319, one oct each
    u16 vv[8];
    *(uint4*)vv = *(const uint4*)&combined[m * 2560 + t * 8];
    float f[8]; float s = 0.f, s2 = 0.f;
#pragma unroll
    for (int k = 0; k < 8; k++) { f[k] = b2f(vv[k]); s += f[k]; s2 += f[k] * f[k]; }
#pragma unroll
    for (int ofs = 1; ofs < 64; ofs <<= 1) {
        s  += __shfl_xor(s, ofs, 64);
        s2 += __shfl_xor(s2, ofs, 64);
    }
    __shared__ float shs[5], shs2[5];
    int wv = t >> 6;
    if ((t & 63) == 0) { shs[wv] = s; shs2[wv] = s2; }
    __syncthreads();
    float S = 0.f, S2 = 0.f;
#pragma unroll
    for (int i = 0; i < 5; i++) { S += shs[i]; S2 += shs2[i]; }
    float mean = S * (1.0f / 2560.0f);
    float var  = S2 * (1.0f / 2560.0f) - mean * mean;
    float rstd = rsqrtf(var + 1e-5f);
#pragma unroll
    for (int k = 0; k < 8; k++) {
        int c = t * 8 + k;
        vv[k] = f2b((f[k] - mean) * rstd * g[c] + bb[c]);
    }
    *(uint4*)&combined[m * 2560 + t * 8] = *(const uint4*)vv;
}

// ---------------------------------------------------------------------------
extern "C" void kernel_launch(void* const* d_in, const int* in_sizes, int n_in,
                              void* d_out, int out_size, void* d_ws, size_t ws_size,
                              hipStream_t stream)
{
    const float* x     = (const float*)d_in[0];
    const float* lc_w  = (const float*)d_in[1];
    const float* lc_b  = (const float*)d_in[2];
    const float* cg_w  = (const float*)d_in[3];
    const float* cg_b  = (const float*)d_in[4];
    const float* cp_w  = (const float*)d_in[5];
    const float* cp_b  = (const float*)d_in[6];
    const float* tw_w  = (const float*)d_in[7];
    const float* tw_b  = (const float*)d_in[8];
    const float* omega_scale = (const float*)d_in[9];
    const float* pi0_w = (const float*)d_in[10];
    const float* pi0_b = (const float*)d_in[11];
    const float* pi2_w = (const float*)d_in[12];
    const float* pi2_b = (const float*)d_in[13];
    const float* m1v_w = (const float*)d_in[14];
    const float* m1v_b = (const float*)d_in[15];
    const float* m1o_w = (const float*)d_in[16];
    const float* m1o_b = (const float*)d_in[17];
    const float* mag_w = (const float*)d_in[18];
    const float* mag_b = (const float*)d_in[19];
    const float* mag_scale = (const float*)d_in[20];
    const float* qo_w  = (const float*)d_in[21];
    const float* qo_b  = (const float*)d_in[22];
    const float* ke_w  = (const float*)d_in[23];
    const float* ke_b  = (const float*)d_in[24];
    const float* ve_w  = (const float*)d_in[25];
    const float* ve_b  = (const float*)d_in[26];
    const float* sk0_w = (const float*)d_in[27];
    const float* sk0_b = (const float*)d_in[28];
    const float* sk2_w = (const float*)d_in[29];
    const float* sk2_b = (const float*)d_in[30];
    const float* sg_w  = (const float*)d_in[31];
    const float* sg_b  = (const float*)d_in[32];
    const float* kvo_w = (const float*)d_in[33];
    const float* kvo_b = (const float*)d_in[34];
    const float* ln_g  = (const float*)d_in[35];
    const float* ln_b  = (const float*)d_in[36];
    const float* o1_w  = (const float*)d_in[37];
    const float* o1_b  = (const float*)d_in[38];
    const float* o2_w  = (const float*)d_in[39];
    const float* o2_b  = (const float*)d_in[40];
    float* out = (float*)d_out;

    char* base = (char*)d_ws;
    size_t off = 0;
    auto alloc = [&](size_t bytes) -> void* {
        void* p = base + off;
        off += (bytes + 255) & ~(size_t)255;
        return p;
    };

    u16*   wcat1  = (u16*)  alloc((size_t)2560 * 512 * 2);
    float* bcat1  = (float*)alloc(2560 * 4);
    u16*   kesgw  = (u16*)  alloc((size_t)256 * 512 * 2);
    float* kesgb  = (float*)alloc(256 * 4);
    u16*   pi2w   = (u16*)  alloc((size_t)512 * 512 * 2);
    u16*   cpw    = (u16*)  alloc((size_t)512 * 512 * 2);
    u16*   sk0w   = (u16*)  alloc((size_t)512 * 1024 * 2);
    u16*   sk2w   = (u16*)  alloc((size_t)128 * 512 * 2);
    u16*   m1ow   = (u16*)  alloc((size_t)512 * 512 * 2);
    u16*   o1w    = (u16*)  alloc((size_t)1024 * 2560 * 2);
    u16*   o2w    = (u16*)  alloc((size_t)512 * 1024 * 2);
    // big transient buffers
    u16*   xcat   = (u16*)  alloc((size_t)BL * 1024 * 2);       // 16.8 MB
    u16*   out1   = (u16*)  alloc((size_t)BL * 2560 * 2);       // 41.9 MB
    u16*   phib   = (u16*)  alloc((size_t)BL * 512 * 2);        // 8.4 MB (bf16)
    float* phi    = (float*)alloc((size_t)BL * 512 * 4);        // 16.8 MB
    float* kesgo  = (float*)alloc((size_t)BL * 144 * 4);
    u16*   convg  = (u16*)  alloc((size_t)BL * 512 * 2);
    float* sppre  = (float*)alloc((size_t)BL * 128 * 4);
    u16*   combined = (u16*)alloc((size_t)BL * 2560 * 2);
    float* cs_o   = (float*)alloc((size_t)4 * 16 * 512 * 4);
    float* cs_x   = (float*)alloc((size_t)4 * 16 * 512 * 4);
    float* cs_m   = (float*)alloc((size_t)4 * 16 * 512 * 4);
    float* cs_wc  = (float*)alloc((size_t)4 * 16 * 512 * 4);
    float* cs_ws  = (float*)alloc((size_t)4 * 16 * 512 * 4);
    float* gni    = (float*)alloc((size_t)BL * 4);
    // aliases onto dead buffers (liveness):
    u16*   posret = convg;                 // convg dead after mega1
    u16*   sk0g   = out1;                  // out1 dead after scan_e
    float* spc    = phi;                   // phi dead after scan_e (first 8.4 MB)
    float* sps    = phi + (size_t)BL * 128;
    float* kvcs   = (float*)phib;          // phib dead after scan_c: 4*256*2048*4 = 8.39 MB = phib size exactly
    float* kvex   = phi + (size_t)BL * 256; // second half of phi (8.39 MB free after spc/sps)
    u16*   o1g    = xcat;                  // xcat dead after mega2
    (void)ws_size; (void)in_sizes; (void)n_in; (void)out_size;

    const size_t SMEM = 49152;             // 3-slot LDS ring

    // 1. weight prep
    prep_weights<<<23307, 256, 0, stream>>>(
        tw_w, pi0_w, m1v_w, mag_w, qo_w, ke_w, ve_w, sg_w,
        pi2_w, cp_w, sk0_w, sk2_w, m1o_w, o1_w, o2_w,
        tw_b, pi0_b, m1v_b, mag_b, qo_b, ke_b, ve_b, sg_b,
        wcat1, bcat1, kesgw, kesgb, pi2w, cpw, sk0w, sk2w, m1ow, o1w, o2w);
    // 2. conv branch input + cast x into xcat
    conv_gate<<<16384, 256, 0, stream>>>(x, lc_w, lc_b, cg_w, cg_b, convg, xcat);
    // 3. mega1: pass1 [omega | gelu(pi0) | v1 | mag | qoff] + ke/ve/sg + conv proj
    mega1<<<dim3(64, 26), 512, SMEM, stream>>>(xcat, convg, wcat1, bcat1,
                                               kesgw, kesgb, cpw, cp_b,
                                               out1, kesgo, combined);
    // 4. stage2: pi2 -> phib (bf16) + scan_a + gate scan, one dispatch
    stage2<<<769, 512, SMEM, stream>>>(out1, pi2w, pi2_b, phib,
                                       x, omega_scale, mag_scale,
                                       cs_o, cs_x, cs_m, kesgo, gni);
    // 5-6. chunked scans (512 threads: 16 rows/thread, 16 waves/CU)
    scan_c<<<512, 512, 0, stream>>>(out1, phib, omega_scale, mag_scale, cs_o,
                                    phi, cs_wc, cs_ws);
    scan_e<<<512, 512, 0, stream>>>(out1, phi, x, mag_scale, cs_m, cs_x, cs_wc, cs_ws,
                                    posret, xcat, combined);
    // 7. mega2: pos_out + sk0(gelu)
    mega2<<<dim3(64, 8), 512, SMEM, stream>>>(posret, xcat, m1ow, m1o_b,
                                              sk0w, sk0_b, combined, sk0g);
    // 8. sk2 -> storage phase pre-tanh (split-K=4, atomic f32)
    hipMemsetAsync(sppre, 0, (size_t)BL * 128 * 4, stream);
    gemm256<EPI_ATOMIC><<<dim3(64, 1, 4), 512, SMEM, stream>>>(sk0g, 512, sk2w, 512, sk2_b,
                                                               sppre, 128, 128, 128, nullptr);
    // 9-11. KV memory (chunk=8, 256 chunks/batch -> 1024 blocks, 4 waves/CU)
    kv_chunk<<<4 * NC_, 64, 0, stream>>>(sppre, kesgo, spc, sps, kvcs);
    kv_scan<<<32, 256, 0, stream>>>(kvcs, kvex);
    kv_retrieve<<<4 * NC_, 64, 0, stream>>>(spc, sps, kesgo, gni, kvex, kvo_w, kvo_b, combined);
    // 12. layernorm in place
    ln_rows<<<8192, 320, 0, stream>>>(combined, ln_g, ln_b);
    // 13. o1 + gelu -> o1g
    gemm256<EPI_GELU_BF16><<<dim3(64, 8), 512, SMEM, stream>>>(combined, 2560, o1w, 2560, o1_b,
                                                               o1g, 1024, 1024, 2560, nullptr);
    // 14. o2 + residual -> out
    gemm256<EPI_RESID_F32><<<dim3(64, 4), 512, SMEM, stream>>>(o1g, 1024, o2w, 1024, o2_b,
                                                               out, 512, 512, 1024, x);
}

// Round 11
// 485.037 us; speedup vs baseline: 1.1930x; 1.0422x over previous
//
#include <hip/hip_runtime.h>
#include <cstdint>

typedef unsigned short u16;
typedef short short8 __attribute__((ext_vector_type(8)));
typedef float floatx4 __attribute__((ext_vector_type(4)));

#define B_ 4
#define L_ 2048
#define D_ 512
#define P_ 128
#define V_ 8
#define BL (B_ * L_)        // 8192
#define NC_ 256             // KV chunks per batch
#define CH_ 8               // KV chunk length
#define NG_ 8               // kv_scan groups (NC_/32)
#define PI_F 3.14159265358979323846f

__device__ inline u16 f2b(float f) {
    unsigned u = __float_as_uint(f);
    unsigned r = u + 0x7FFFu + ((u >> 16) & 1u);
    return (u16)(r >> 16);
}
__device__ inline float b2f(u16 h) {
    return __uint_as_float(((unsigned)h) << 16);
}
__device__ inline float gelu_f(float v) {
    return 0.5f * v * (1.0f + erff(v * 0.70710678118654752f));
}
__device__ inline float sigm(float v) {
    return 1.0f / (1.0f + __expf(-v));
}
__device__ inline float tanh_fast(float v) {
    return 1.0f - 2.0f / (1.0f + __expf(2.0f * v));
}

// async global->LDS, 16B per lane. LDS dest is wave-uniform base + lane*16.
__device__ inline void async16(const u16* g, u16* l) {
    __builtin_amdgcn_global_load_lds(
        (const __attribute__((address_space(1))) unsigned int*)g,
        (__attribute__((address_space(3))) unsigned int*)l, 16, 0, 0);
}

extern __shared__ u16 smem_dyn[];   // 49152 B: 3-slot ring of (A 8KB + B 8KB)

// ---------------------------------------------------------------------------
// 128x128-tile bf16 MFMA GEMM body, BK=32, COMPILE-TIME epilogue.
// R11 = R10 GEMM verbatim (best measured: total 505us, o1 68.7us).
// 8 waves (512 thr), 2x4 wave grid, 64x32 output per wave, acc[4][2]
// -> 16 waves/CU at 2 blocks/CU.  LDS-BW-saturated at this shape (96KB
// reads + 32KB writes per CU per K-step ~= the whole K-step); alternative
// shapes (R4 barrier-free, R6 k-split, R9 BN=64) all regressed -> parked.
//   * T2 XOR-swizzle (0 bank conflicts measured).
//   * Fragment double-buffer: frag t+1 ds_read during MFMA t.
//   * 3-slot ring, stage(t+3) after barrier, prefetch depth 2 K-steps.
//   * Per-iter: lgkm(0) -> vmcnt(2) -> barrier -> stage(t+3) ->
//     ds_read frag t+1 || 8xMFMA t.  Prologue 6 outstanding -> vmcnt(4).
// Requires nsteps = K/32 EVEN and >= 4 (call sites: K in {128,512,1024,2560}).
// ---------------------------------------------------------------------------
enum { EPI_F32 = 0, EPI_BF16 = 1, EPI_GELU_BF16 = 2, EPI_RESID_F32 = 3,
       EPI_PASS1 = 4, EPI_ATOMIC = 5 };

template <int EPI>
__device__ __forceinline__ void gemm_body(
    const u16* __restrict__ A, int lda,
    const u16* __restrict__ W, int ldw,
    const float* __restrict__ bias,
    void* __restrict__ Cout, int ldc, int N, int K,
    const float* __restrict__ resid, int mt, int nt)
{
    const int tid  = threadIdx.x;
    const int lane = tid & 63;
    const int wid  = tid >> 6;               // 0..7
    const int wm   = wid & 1, wn = wid >> 1; // 2 x 4 wave grid
    const int l16  = lane & 15, quad = lane >> 4;
    const int rswz = (l16 >> 1) & 3;          // read-side cg XOR ((row>>1)&3)

    floatx4 acc[4][2] = {};

    const u16* Ab = A + (size_t)(mt * 128) * lda;
    const u16* Wb = W + (size_t)(nt * 128) * ldw;

    const int srow = lane >> 2;
    // source column pre-swizzled so linear LDS write lands swizzled data
    const int scol = ((lane & 3) ^ ((srow >> 1) & 3)) * 8;
    // wave w stages A rows [16w,16w+16) and B rows [16w,16w+16) of the tile
    const u16* ga0 = Ab + (size_t)(wid * 16 + srow) * lda + scol;
    const u16* gb0 = Wb + (size_t)(wid * 16 + srow) * ldw + scol;
    const int lW = wid * 512;                 // wave-uniform LDS chunk (u16)

    const int nsteps = K >> 5;

    auto stage = [&](int t, int s) {
        u16* base = smem_dyn + s * 8192;      // 8192 u16 = 16KB per slot
        const int ko = t * 32;
        async16(ga0 + ko, base + lW);
        async16(gb0 + ko, base + 4096 + lW);
    };

    auto readfrag = [&](int slot, short8 (&a)[4], short8 (&b)[2]) {
        const u16* As = smem_dyn + slot * 8192;
        const u16* Bs = As + 4096;
#pragma unroll
        for (int i = 0; i < 4; i++)
            a[i] = *(const short8*)(&As[(wm * 64 + i * 16 + l16) * 32 + (quad ^ rswz) * 8]);
#pragma unroll
        for (int j = 0; j < 2; j++)
            b[j] = *(const short8*)(&Bs[(wn * 32 + j * 16 + l16) * 32 + (quad ^ rswz) * 8]);
    };

    auto mfma8 = [&](short8 (&a)[4], short8 (&b)[2]) {
        __builtin_amdgcn_s_setprio(1);
#pragma unroll
        for (int i = 0; i < 4; i++)
#pragma unroll
            for (int j = 0; j < 2; j++)
                acc[i][j] = __builtin_amdgcn_mfma_f32_16x16x32_bf16(a[i], b[j], acc[i][j], 0, 0, 0);
        __builtin_amdgcn_s_setprio(0);
    };

    // prologue: fill the ring (2 loads/stage -> 6 outstanding), confirm stage 0
    stage(0, 0);
    if (nsteps > 1) stage(1, 1);
    if (nsteps > 2) stage(2, 2);
    if (nsteps > 2)      asm volatile("s_waitcnt vmcnt(4)" ::: "memory");
    else if (nsteps > 1) asm volatile("s_waitcnt vmcnt(2)" ::: "memory");
    else                 asm volatile("s_waitcnt vmcnt(0)" ::: "memory");
    __builtin_amdgcn_s_barrier();
    asm volatile("" ::: "memory");

    short8 aE[4], bE[2], aO[4], bO[2];
    readfrag(0, aE, bE);

    for (int t = 0; t < nsteps; t += 2) {
        // ---- even iter: consume set E, prefetch set O ----
        asm volatile("s_waitcnt lgkmcnt(0)" ::: "memory");   // frag t in regs
        if (t + 2 < nsteps)      asm volatile("s_waitcnt vmcnt(2)" ::: "memory");
        else if (t + 1 < nsteps) asm volatile("s_waitcnt vmcnt(0)" ::: "memory");
        __builtin_amdgcn_s_barrier();
        asm volatile("" ::: "memory");
        if (t + 3 < nsteps) stage(t + 3, t % 3);
        if (t + 1 < nsteps) readfrag((t + 1) % 3, aO, bO);
        mfma8(aE, bE);
        // ---- odd iter: consume set O, prefetch set E ----
        const int t1 = t + 1;                                 // < nsteps (even nsteps)
        asm volatile("s_waitcnt lgkmcnt(0)" ::: "memory");
        if (t1 + 2 < nsteps)      asm volatile("s_waitcnt vmcnt(2)" ::: "memory");
        else if (t1 + 1 < nsteps) asm volatile("s_waitcnt vmcnt(0)" ::: "memory");
        __builtin_amdgcn_s_barrier();
        asm volatile("" ::: "memory");
        if (t1 + 3 < nsteps) stage(t1 + 3, t1 % 3);
        if (t1 + 1 < nsteps) readfrag((t1 + 1) % 3, aE, bE);
        mfma8(aO, bO);
    }

#pragma unroll
    for (int i = 0; i < 4; i++) {
#pragma unroll
        for (int j = 0; j < 2; j++) {
#pragma unroll
            for (int r = 0; r < 4; r++) {
                int grow = mt * 128 + wm * 64 + i * 16 + quad * 4 + r;
                int gcol = nt * 128 + wn * 32 + j * 16 + l16;
                if (gcol < N) {
                    float v = acc[i][j][r] + (bias ? bias[gcol] : 0.0f);
                    size_t off = (size_t)grow * ldc + gcol;
                    if (EPI == EPI_F32)            ((float*)Cout)[off] = v;
                    else if (EPI == EPI_BF16)      ((u16*)Cout)[off] = f2b(v);
                    else if (EPI == EPI_GELU_BF16) ((u16*)Cout)[off] = f2b(gelu_f(v));
                    else if (EPI == EPI_PASS1) {
                        float vv = (gcol >= 512 && gcol < 1024) ? gelu_f(v) : v;
                        ((u16*)Cout)[off] = f2b(vv);
                    }
                    else if (EPI == EPI_RESID_F32) ((float*)Cout)[off] = v + resid[off];
                    else                           atomicAdd(&((float*)Cout)[off], v);
                }
            }
        }
    }
}

// generic GEMM; grid.z = split-K slice (A,W advance by kz*K along k; bias slice 0)
template <int EPI>
__global__ __launch_bounds__(512)
void gemm256(const u16* __restrict__ A, int lda,
             const u16* __restrict__ W, int ldw,
             const float* __restrict__ bias,
             void* __restrict__ C, int ldc, int N, int K,
             const float* __restrict__ resid)
{
    int kz = blockIdx.z;
    gemm_body<EPI>(A + (size_t)kz * K, lda, W + (size_t)kz * K, ldw,
                   kz == 0 ? bias : nullptr, C, ldc, N, K, resid,
                   blockIdx.x, blockIdx.y);
}

// pass1 (N=2560,y 0..19) + ke/ve/sg (N=144,y 20..21) + conv proj (y 22..25)
__global__ __launch_bounds__(512)
void mega1(const u16* __restrict__ xcat, const u16* __restrict__ convg,
           const u16* __restrict__ wcat1, const float* __restrict__ bcat1,
           const u16* __restrict__ kesgw, const float* __restrict__ kesgb,
           const u16* __restrict__ cpw, const float* __restrict__ cp_b,
           u16* __restrict__ out1, float* __restrict__ kesgo, u16* __restrict__ combined)
{
    int y = blockIdx.y, mt = blockIdx.x;
    if (y < 20)
        gemm_body<EPI_PASS1>(xcat, 1024, wcat1, 512, bcat1, out1, 2560, 2560, 512, nullptr, mt, y);
    else if (y < 22)
        gemm_body<EPI_F32>(xcat, 1024, kesgw, 512, kesgb, kesgo, 144, 144, 512, nullptr, mt, y - 20);
    else
        gemm_body<EPI_BF16>(convg, 512, cpw, 512, cp_b, combined, 2560, 512, 512, nullptr, mt, y - 22);
}

// pos_out (y 0..3) + sk0 (y 4..7)
__global__ __launch_bounds__(512)
void mega2(const u16* __restrict__ posret, const u16* __restrict__ xcat,
           const u16* __restrict__ m1ow, const float* __restrict__ m1o_b,
           const u16* __restrict__ sk0w, const float* __restrict__ sk0_b,
           u16* __restrict__ combined, u16* __restrict__ sk0g)
{
    int y = blockIdx.y, mt = blockIdx.x;
    if (y < 4)
        gemm_body<EPI_BF16>(posret, 512, m1ow, 512, m1o_b, combined + 512, 2560, 512, 512, nullptr, mt, y);
    else
        gemm_body<EPI_GELU_BF16>(xcat, 1024, sk0w, 1024, sk0_b, sk0g, 512, 512, 1024, nullptr, mt, y - 4);
}

// ---------------------------------------------------------------------------
// Weight prep: cast fp32 weights -> bf16, build concatenations + pads.
// ---------------------------------------------------------------------------
__global__ __launch_bounds__(256)
void prep_weights(const float* tw, const float* pi0, const float* m1v, const float* mag, const float* qo,
                  const float* ke, const float* ve, const float* sg,
                  const float* pi2, const float* cp, const float* sk0, const float* sk2,
                  const float* m1o, const float* o1, const float* o2,
                  const float* tw_b, const float* pi0_b, const float* m1v_b, const float* mag_b, const float* qo_b,
                  const float* ke_b, const float* ve_b, const float* sg_b,
                  u16* wcat1, float* bcat1, u16* kesgw, float* kesgb,
                  u16* pi2w, u16* cpw, u16* sk0w, u16* sk2w, u16* m1ow, u16* o1w, u16* o2w)
{
    int idx = blockIdx.x * 256 + threadIdx.x;
    const int n0 = 2560 * 512;
    const int n1 = n0 + 256 * 512;
    const int n2 = n1 + 512 * 512;
    const int n3 = n2 + 512 * 512;
    const int n4 = n3 + 512 * 1024;
    const int n5 = n4 + 128 * 512;
    const int n6 = n5 + 512 * 512;
    const int n7 = n6 + 1024 * 2560;
    const int n8 = n7 + 512 * 1024;
    const int n9 = n8 + 2560;
    const int n10 = n9 + 256;
    if (idx < n0) {
        int r = idx >> 9, k = idx & 511;
        const float* s = (r < 512) ? tw : (r < 1024) ? pi0 : (r < 1536) ? m1v : (r < 2048) ? mag : qo;
        wcat1[idx] = f2b(s[(r & 511) * 512 + k]);
    } else if (idx < n1) {
        int i = idx - n0; int r = i >> 9, k = i & 511;
        float v;
        if (r < 128)      v = ke[r * 512 + k];
        else if (r < 136) v = ve[(r - 128) * 512 + k];
        else if (r == 136) v = sg[k];
        else               v = 0.0f;
        kesgw[i] = f2b(v);
    }
    else if (idx < n2) { int i = idx - n1; pi2w[i] = f2b(pi2[i]); }
    else if (idx < n3) { int i = idx - n2; cpw[i]  = f2b(cp[i]); }
    else if (idx < n4) { int i = idx - n3; sk0w[i] = f2b(sk0[i]); }
    else if (idx < n5) { int i = idx - n4; sk2w[i] = f2b(sk2[i]); }
    else if (idx < n6) { int i = idx - n5; m1ow[i] = f2b(m1o[i]); }
    else if (idx < n7) { int i = idx - n6; o1w[i]  = f2b(o1[i]); }
    else if (idx < n8) { int i = idx - n7; o2w[i]  = f2b(o2[i]); }
    else if (idx < n9) {
        int i = idx - n8;
        const float* s = (i < 512) ? tw_b : (i < 1024) ? pi0_b : (i < 1536) ? m1v_b : (i < 2048) ? mag_b : qo_b;
        bcat1[i] = s[i & 511];
    } else if (idx < n10) {
        int i = idx - n9;
        kesgb[i] = (i < 128) ? ke_b[i] : (i < 136) ? ve_b[i - 128] : (i == 136) ? sg_b[0] : 0.0f;
    }
}

// depthwise causal conv (K=4) gated branch + cast x into xcat cols [0,512)
// R11: float4-vectorized — each thread computes 4 d-channels (16B/lane loads,
// G13 sweet spot; x elements fetched once per tap instead of 4x scalar).
__global__ __launch_bounds__(256)
void conv_gate(const float* __restrict__ x,
               const float* __restrict__ lcw, const float* __restrict__ lcb,
               const float* __restrict__ cgw, const float* __restrict__ cgb,
               u16* __restrict__ out, u16* __restrict__ xcat)
{
    int idx = blockIdx.x * 256 + threadIdx.x;   // over BL*128
    int d4 = (idx & 127) * 4; int bl = idx >> 7;
    int l = bl & (L_ - 1); int b = bl >> 11;
    float4 xr[4];
#pragma unroll
    for (int k = 0; k < 4; k++) xr[k] = make_float4(0.f, 0.f, 0.f, 0.f);
#pragma unroll
    for (int k = 0; k < 4; k++) {
        int ls = l - 3 + k;
        if (ls >= 0)
            xr[k] = *(const float4*)&x[((size_t)(b * L_ + ls)) * 512 + d4];
    }
    float4 lw[4], cw[4];
#pragma unroll
    for (int j = 0; j < 4; j++) {
        lw[j] = *(const float4*)&lcw[(d4 + j) * 4];
        cw[j] = *(const float4*)&cgw[(d4 + j) * 4];
    }
    float4 lb = *(const float4*)&lcb[d4];
    float4 cb = *(const float4*)&cgb[d4];
    u16 outv[4], xcv[4];
#pragma unroll
    for (int j = 0; j < 4; j++) {
        float xk0 = (&xr[0].x)[j], xk1 = (&xr[1].x)[j],
              xk2 = (&xr[2].x)[j], xk3 = (&xr[3].x)[j];
        float a0 = (&lb.x)[j] + xk0 * (&lw[j].x)[0] + xk1 * (&lw[j].x)[1]
                              + xk2 * (&lw[j].x)[2] + xk3 * (&lw[j].x)[3];
        float a1 = sigm((&cb.x)[j] + xk0 * (&cw[j].x)[0] + xk1 * (&cw[j].x)[1]
                                   + xk2 * (&cw[j].x)[2] + xk3 * (&cw[j].x)[3]);
        outv[j] = f2b(a0 * a1);
        xcv[j]  = f2b(xk3);
    }
    *(uint2*)&out[(size_t)bl * 512 + d4]         = *(const uint2*)outv;
    *(uint2*)&xcat[(size_t)bl * 1024 + d4]       = *(const uint2*)xcv;
}

// ---------------------------------------------------------------------------
// scan_a body (512-thread version): per-chunk sums of omega/mag/x.
// blk = b(4) x dt(8) x nc(16).  8 groups of 64 lanes, 16 rows each.
// ---------------------------------------------------------------------------
__device__ __forceinline__ void scan_a_body(
    int blk, const u16* __restrict__ out1, const float* __restrict__ x,
    const float* __restrict__ oscale, const float* __restrict__ msc,
    float* __restrict__ cs_o, float* __restrict__ cs_x, float* __restrict__ cs_m)
{
    int nc = blk & 15, dt = (blk >> 4) & 7, b = blk >> 7;
    int t = threadIdx.x; int dl = t & 63, lg = t >> 6;   // lg 0..7
    int d = dt * 64 + dl;
    float os = fabsf(oscale[d]);
    float ms = fabsf(msc[0]);
    float so = 0.f, sx = 0.f, sm = 0.f;
    int l0 = nc * 128 + lg * 16;
    for (int i = 0; i < 16; i++) {
        size_t r = (size_t)(b * L_ + l0 + i);
        so += b2f(out1[r * 2560 + d]) * os;
        sm += sigm(b2f(out1[r * 2560 + 1536 + d])) * ms;
        sx += x[r * 512 + d];
    }
    __shared__ float sh[3][8][64];
    sh[0][lg][dl] = so; sh[1][lg][dl] = sx; sh[2][lg][dl] = sm;
    __syncthreads();
    if (t < 64) {
        float a = 0.f, xx = 0.f, m = 0.f;
        for (int g = 0; g < 8; g++) { a += sh[0][g][t]; xx += sh[1][g][t]; m += sh[2][g][t]; }
        size_t o = ((size_t)(b * 16 + nc)) * 512 + dt * 64 + t;
        cs_o[o] = a; cs_x[o] = xx; cs_m[o] = m;
    }
}

// store-gate scan: wave w handles batch w (waves 0..3 of the block; no barrier).
__device__ __forceinline__ void gate_body(const float* __restrict__ kesgo,
                                          float* __restrict__ gni)
{
    if (threadIdx.x >= 256) return;           // waves 4..7 idle (no barrier here)
    int b = threadIdx.x >> 6; int lane = threadIdx.x & 63;
    float v[32]; float s = 0.f;
#pragma unroll
    for (int i = 0; i < 32; i++) {
        int l = lane * 32 + i;
        v[i] = sigm(kesgo[((size_t)(b * L_ + l)) * 144 + 136]);
        s += v[i];
    }
    float sc = s;
#pragma unroll
    for (int ofs = 1; ofs < 64; ofs <<= 1) {
        float t = __shfl_up(sc, ofs, 64);
        if (lane >= ofs) sc += t;
    }
    float run = sc - s;   // exclusive prefix
#pragma unroll
    for (int i = 0; i < 32; i++) {
        run += v[i];
        gni[b * L_ + lane * 32 + i] = rsqrtf(fmaxf(run, 1.0f));
    }
}

// fused: pi2 GEMM (blocks 0..255) + scan_a (256..767) + gate scan (768)
__global__ __launch_bounds__(512)
void stage2(const u16* __restrict__ out1, const u16* __restrict__ pi2w,
            const float* __restrict__ pi2_b, u16* __restrict__ phib,
            const float* __restrict__ x, const float* __restrict__ oscale,
            const float* __restrict__ msc,
            float* __restrict__ cs_o, float* __restrict__ cs_x, float* __restrict__ cs_m,
            const float* __restrict__ kesgo, float* __restrict__ gni)
{
    int blk = blockIdx.x;
    if (blk < 256)
        gemm_body<EPI_BF16>(out1 + 512, 2560, pi2w, 512, pi2_b, phib, 512, 512, 512,
                            nullptr, blk & 63, blk >> 6);
    else if (blk < 768)
        scan_a_body(blk - 256, out1, x, oscale, msc, cs_o, cs_x, cs_m);
    else
        gate_body(kesgo, gni);
}

// scan_c (512 threads, 16 rows/thread — R8 latency-regime widening, kept).
__global__ __launch_bounds__(512)
void scan_c(const u16* __restrict__ out1, const u16* __restrict__ phib,
            const float* __restrict__ oscale, const float* __restrict__ msc,
            const float* __restrict__ cs_o,
            float* __restrict__ phi, float* __restrict__ cs_wc, float* __restrict__ cs_ws)
{
    int blk = blockIdx.x;
    int nc = blk & 15, dt = (blk >> 4) & 7, b = blk >> 7;
    int t = threadIdx.x; int dl = t & 63, lg = t >> 6;   // lg 0..7
    int d = dt * 64 + dl;
    float os = fabsf(oscale[d]);
    float ms = fabsf(msc[0]);
    int l0 = nc * 128 + lg * 16;
    float so = 0.f;
    for (int i = 0; i < 16; i++) {
        size_t r = (size_t)(b * L_ + l0 + i);
        so += b2f(out1[r * 2560 + d]) * os;
    }
    __shared__ float sh[8][64];
    __shared__ float shw[2][8][64];
    sh[lg][dl] = so;
    __syncthreads();
    float pre = 0.f;
    for (int p = 0; p < nc; p++) pre += cs_o[((size_t)(b * 16 + p)) * 512 + d];
    for (int g = 0; g < lg; g++) pre += sh[g][dl];
    float cum = pre, swc = 0.f, sws = 0.f;
    for (int i = 0; i < 16; i++) {
        size_t r = (size_t)(b * L_ + l0 + i);
        cum += b2f(out1[r * 2560 + d]) * os;
        float ph = b2f(phib[r * 512 + d]) + cum;
        phi[r * 512 + d] = ph;
        float mg = sigm(b2f(out1[r * 2560 + 1536 + d])) * ms;
        float wv = mg * b2f(out1[r * 2560 + 1024 + d]);
        float s = __sinf(ph), c = __cosf(ph);
        swc += wv * c; sws += wv * s;
    }
    shw[0][lg][dl] = swc; shw[1][lg][dl] = sws;
    __syncthreads();
    if (t < 64) {
        float a = 0.f, bb = 0.f;
        for (int g = 0; g < 8; g++) { a += shw[0][g][t]; bb += shw[1][g][t]; }
        size_t o = ((size_t)(b * 16 + nc)) * 512 + dt * 64 + t;
        cs_wc[o] = a; cs_ws[o] = bb;
    }
}

// scan_e (512 threads, 16 rows/thread — R8 widening, kept).
__global__ __launch_bounds__(512)
void scan_e(const u16* __restrict__ out1, const float* __restrict__ phi,
            const float* __restrict__ x, const float* __restrict__ msc,
            const float* __restrict__ cs_m, const float* __restrict__ cs_x,
            const float* __restrict__ cs_wc, const float* __restrict__ cs_ws,
            u16* __restrict__ posret, u16* __restrict__ xcat, u16* __restrict__ combined)
{
    int blk = blockIdx.x;
    int nc = blk & 15, dt = (blk >> 4) & 7, b = blk >> 7;
    int t = threadIdx.x; int dl = t & 63, lg = t >> 6;   // lg 0..7
    int d = dt * 64 + dl;
    float ms = fabsf(msc[0]);
    int l0 = nc * 128 + lg * 16;
    float sm = 0.f, swc = 0.f, sws = 0.f, sx = 0.f;
    for (int i = 0; i < 16; i++) {
        size_t r = (size_t)(b * L_ + l0 + i);
        float ph = phi[r * 512 + d];
        float mg = sigm(b2f(out1[r * 2560 + 1536 + d])) * ms;
        float wv = mg * b2f(out1[r * 2560 + 1024 + d]);
        float s = __sinf(ph), c = __cosf(ph);
        sm += mg; swc += wv * c; sws += wv * s; sx += x[r * 512 + d];
    }
    __shared__ float sh[4][8][64];
    sh[0][lg][dl] = sm; sh[1][lg][dl] = swc; sh[2][lg][dl] = sws; sh[3][lg][dl] = sx;
    __syncthreads();
    float cm = 0.f, cwc = 0.f, cws = 0.f, cx = 0.f;
    for (int p = 0; p < nc; p++) {
        size_t o = ((size_t)(b * 16 + p)) * 512 + d;
        cm += cs_m[o]; cwc += cs_wc[o]; cws += cs_ws[o]; cx += cs_x[o];
    }
    for (int g = 0; g < lg; g++) {
        cm += sh[0][g][dl]; cwc += sh[1][g][dl]; cws += sh[2][g][dl]; cx += sh[3][g][dl];
    }
    const float invsqD = 0.044194173824159216f;  // 1/sqrt(512)
    for (int i = 0; i < 16; i++) {
        int l = l0 + i;
        size_t r = (size_t)(b * L_ + l);
        float ph = phi[r * 512 + d];
        float mg = sigm(b2f(out1[r * 2560 + 1536 + d])) * ms;
        float wv = mg * b2f(out1[r * 2560 + 1024 + d]);
        float xv = x[r * 512 + d];
        float s = __sinf(ph), c = __cosf(ph);
        cm += mg; cwc += wv * c; cws += wv * s; cx += xv;
        float smag = sqrtf(cm + 1e-8f);
        float m1c = cwc / smag, m1s = cws / smag;
        float phq = ph + b2f(out1[r * 2560 + 2048 + d]);
        float sq = __sinf(phq), cq = __cosf(phq);
        float pr = (m1c * cq + m1s * sq) * invsqD;
        posret[r * 512 + d] = f2b(pr);
        xcat[r * 1024 + 512 + d] = f2b(cx / (float)(l + 1));
        combined[r * 2560 + 1536 + d] = f2b(xv * c);
        combined[r * 2560 + 2048 + d] = f2b(xv * s);
    }
}

// KV chunk-state sums + materialize sincos(storage_phase).
// NC_=256, CH_=8: 1024 blocks (4 waves/CU).  Lane t covers p=t,p+64.
__global__ __launch_bounds__(64)
void kv_chunk(const float* __restrict__ sppre, const float* __restrict__ kesgo,
              float* __restrict__ spc, float* __restrict__ sps,
              float* __restrict__ csum)
{
    int blk = blockIdx.x; int nc = blk & (NC_ - 1), b = blk >> 8;
    int t = threadIdx.x;
    float Sc[2][8] = {}, Ss[2][8] = {};
    for (int i = 0; i < CH_; i++) {
        size_t r = (size_t)(b * L_ + nc * CH_ + i);
        float sgate = sigm(kesgo[r * 144 + 136]);
        float g[8];
#pragma unroll
        for (int v = 0; v < 8; v++) g[v] = kesgo[r * 144 + 128 + v] * sgate;
#pragma unroll
        for (int j = 0; j < 2; j++) {
            int p = t + j * 64;
            float sp = tanh_fast(sppre[r * 128 + p]) * PI_F;
            float s = __sinf(sp), c = __cosf(sp);
            spc[r * 128 + p] = c; sps[r * 128 + p] = s;
#pragma unroll
            for (int v = 0; v < 8; v++) { Sc[j][v] += c * g[v]; Ss[j][v] += s * g[v]; }
        }
    }
    size_t base = (size_t)blk * 2048;
#pragma unroll
    for (int j = 0; j < 2; j++)
#pragma unroll
        for (int v = 0; v < 8; v++) {
            csum[base + (t + j * 64) * 8 + v]        = Sc[j][v];
            csum[base + 1024 + (t + j * 64) * 8 + v] = Ss[j][v];
        }
}

// R11 two-phase kv scan (was 32 blocks x 256 serial iters = 0.125 waves/SIMD).
// Phase p: per-group partial sums.  Work item (b, g, cs, pv): 65536 threads.
__global__ __launch_bounds__(256)
void kv_scan_p(const float* __restrict__ cin, float* __restrict__ part)
{
    int t = blockIdx.x * 256 + threadIdx.x;
    int pv = t & 1023; int cs = (t >> 10) & 1; int g = (t >> 11) & (NG_ - 1);
    int b = t >> 14;
    float s = 0.f;
    for (int i = 0; i < NC_ / NG_; i++) {
        int nc = g * (NC_ / NG_) + i;
        s += cin[((size_t)(b * NC_ + nc)) * 2048 + cs * 1024 + pv];
    }
    part[((size_t)((b * 2 + cs) * NG_ + g)) * 1024 + pv] = s;
}

// Phase f: offset by prior-group partials, emit exclusive prefix for own group.
__global__ __launch_bounds__(256)
void kv_scan_f(const float* __restrict__ cin, const float* __restrict__ part,
               float* __restrict__ cex)
{
    int t = blockIdx.x * 256 + threadIdx.x;
    int pv = t & 1023; int cs = (t >> 10) & 1; int g = (t >> 11) & (NG_ - 1);
    int b = t >> 14;
    float run = 0.f;
    for (int gp = 0; gp < g; gp++)
        run += part[((size_t)((b * 2 + cs) * NG_ + gp)) * 1024 + pv];
    for (int i = 0; i < NC_ / NG_; i++) {
        int nc = g * (NC_ / NG_) + i;
        size_t o = ((size_t)(b * NC_ + nc)) * 2048 + cs * 1024 + pv;
        cex[o] = run; run += cin[o];
    }
}

// KV retrieve + fused kv_out linear -> combined cols [1024,1536)
// 1024 blocks (4 waves/CU), CH_=8 serial rows per block.
__global__ __launch_bounds__(64)
void kv_retrieve(const float* __restrict__ spc, const float* __restrict__ sps,
                 const float* __restrict__ kesgo,
                 const float* __restrict__ gni, const float* __restrict__ cex,
                 const float* __restrict__ kvo_w, const float* __restrict__ kvo_b,
                 u16* __restrict__ combined)
{
    int blk = blockIdx.x; int nc = blk & (NC_ - 1), b = blk >> 8;
    int t = threadIdx.x;
    const int nb = t * 8;                 // this lane's 8 output cols
    float wr[8][8], br[8];
#pragma unroll
    for (int n = 0; n < 8; n++) {
        *(float4*)&wr[n][0] = *(const float4*)&kvo_w[(nb + n) * 8];
        *(float4*)&wr[n][4] = *(const float4*)&kvo_w[(nb + n) * 8 + 4];
        br[n] = kvo_b[nb + n];
    }
    float Sc[2][8], Ss[2][8];
    size_t base = (size_t)blk * 2048;
#pragma unroll
    for (int j = 0; j < 2; j++)
#pragma unroll
        for (int v = 0; v < 8; v++) {
            Sc[j][v] = cex[base + (t + j * 64) * 8 + v];
            Ss[j][v] = cex[base + 1024 + (t + j * 64) * 8 + v];
        }
    for (int i = 0; i < CH_; i++) {
        size_t r = (size_t)(b * L_ + nc * CH_ + i);
        float sgate = sigm(kesgo[r * 144 + 136]);
        float g[8];
#pragma unroll
        for (int v = 0; v < 8; v++) g[v] = kesgo[r * 144 + 128 + v] * sgate;
        float part[8];
#pragma unroll
        for (int v = 0; v < 8; v++) part[v] = 0.f;
#pragma unroll
        for (int j = 0; j < 2; j++) {
            int p = t + j * 64;
            float c = spc[r * 128 + p], s = sps[r * 128 + p];
#pragma unroll
            for (int v = 0; v < 8; v++) { Sc[j][v] += c * g[v]; Ss[j][v] += s * g[v]; }
            float qp = tanh_fast(kesgo[r * 144 + p]) * PI_F;
            float sq = __sinf(qp), cq = __cosf(qp);
#pragma unroll
            for (int v = 0; v < 8; v++) part[v] += cq * Sc[j][v] + sq * Ss[j][v];
        }
#pragma unroll
        for (int ofs = 1; ofs < 64; ofs <<= 1)
#pragma unroll
            for (int v = 0; v < 8; v++) part[v] += __shfl_xor(part[v], ofs, 64);
        float scale = gni[r] * 0.08838834764831845f;   // 1/sqrt(128)
        float pv[8];
#pragma unroll
        for (int v = 0; v < 8; v++) pv[v] = part[v] * scale;
        u16 outv[8];
#pragma unroll
        for (int n = 0; n < 8; n++) {
            float a = br[n];
#pragma unroll
            for (int v = 0; v < 8; v++) a += pv[v] * wr[n][v];
            outv[n] = f2b(a);
        }
        *(uint4*)&combined[r * 2560 + 1024 + nb] = *(const uint4*)outv;
    }
}

// layernorm over 2560, in place on bf16 combined.  Block 320 (5 waves), b128 I/O.
__global__ __launch_bounds__(320)
void ln_rows(u16* __restrict__ combined, const float* __restrict__ g, const float* __restrict__ bb)
{
    size_t m = blockIdx.x; int t = threadIdx.x;   // 0..319, one oct each
    u16 vv[8];
    *(uint4*)vv = *(const uint4*)&combined[m * 2560 + t * 8];
    float f[8]; float s = 0.f, s2 = 0.f;
#pragma unroll
    for (int k = 0; k < 8; k++) { f[k] = b2f(vv[k]); s += f[k]; s2 += f[k] * f[k]; }
#pragma unroll
    for (int ofs = 1; ofs < 64; ofs <<= 1) {
        s  += __shfl_xor(s, ofs, 64);
        s2 += __shfl_xor(s2, ofs, 64);
    }
    __shared__ float shs[5], shs2[5];
    int wv = t >> 6;
    if ((t & 63) == 0) { shs[wv] = s; shs2[wv] = s2; }
    __syncthreads();
    float S = 0.f, S2 = 0.f;
#pragma unroll
    for (int i = 0; i < 5; i++) { S += shs[i]; S2 += shs2[i]; }
    float mean = S * (1.0f / 2560.0f);
    float var  = S2 * (1.0f / 2560.0f) - mean * mean;
    float rstd = rsqrtf(var + 1e-5f);
#pragma unroll
    for (int k = 0; k < 8; k++) {
        int c = t * 8 + k;
        vv[k] = f2b((f[k] - mean) * rstd * g[c] + bb[c]);
    }
    *(uint4*)&combined[m * 2560 + t * 8] = *(const uint4*)vv;
}

// ---------------------------------------------------------------------------
extern "C" void kernel_launch(void* const* d_in, const int* in_sizes, int n_in,
                              void* d_out, int out_size, void* d_ws, size_t ws_size,
                              hipStream_t stream)
{
    const float* x     = (const float*)d_in[0];
    const float* lc_w  = (const float*)d_in[1];
    const float* lc_b  = (const float*)d_in[2];
    const float* cg_w  = (const float*)d_in[3];
    const float* cg_b  = (const float*)d_in[4];
    const float* cp_w  = (const float*)d_in[5];
    const float* cp_b  = (const float*)d_in[6];
    const float* tw_w  = (const float*)d_in[7];
    const float* tw_b  = (const float*)d_in[8];
    const float* omega_scale = (const float*)d_in[9];
    const float* pi0_w = (const float*)d_in[10];
    const float* pi0_b = (const float*)d_in[11];
    const float* pi2_w = (const float*)d_in[12];
    const float* pi2_b = (const float*)d_in[13];
    const float* m1v_w = (const float*)d_in[14];
    const float* m1v_b = (const float*)d_in[15];
    const float* m1o_w = (const float*)d_in[16];
    const float* m1o_b = (const float*)d_in[17];
    const float* mag_w = (const float*)d_in[18];
    const float* mag_b = (const float*)d_in[19];
    const float* mag_scale = (const float*)d_in[20];
    const float* qo_w  = (const float*)d_in[21];
    const float* qo_b  = (const float*)d_in[22];
    const float* ke_w  = (const float*)d_in[23];
    const float* ke_b  = (const float*)d_in[24];
    const float* ve_w  = (const float*)d_in[25];
    const float* ve_b  = (const float*)d_in[26];
    const float* sk0_w = (const float*)d_in[27];
    const float* sk0_b = (const float*)d_in[28];
    const float* sk2_w = (const float*)d_in[29];
    const float* sk2_b = (const float*)d_in[30];
    const float* sg_w  = (const float*)d_in[31];
    const float* sg_b  = (const float*)d_in[32];
    const float* kvo_w = (const float*)d_in[33];
    const float* kvo_b = (const float*)d_in[34];
    const float* ln_g  = (const float*)d_in[35];
    const float* ln_b  = (const float*)d_in[36];
    const float* o1_w  = (const float*)d_in[37];
    const float* o1_b  = (const float*)d_in[38];
    const float* o2_w  = (const float*)d_in[39];
    const float* o2_b  = (const float*)d_in[40];
    float* out = (float*)d_out;

    char* base = (char*)d_ws;
    size_t off = 0;
    auto alloc = [&](size_t bytes) -> void* {
        void* p = base + off;
        off += (bytes + 255) & ~(size_t)255;
        return p;
    };

    u16*   wcat1  = (u16*)  alloc((size_t)2560 * 512 * 2);
    float* bcat1  = (float*)alloc(2560 * 4);
    u16*   kesgw  = (u16*)  alloc((size_t)256 * 512 * 2);
    float* kesgb  = (float*)alloc(256 * 4);
    u16*   pi2w   = (u16*)  alloc((size_t)512 * 512 * 2);
    u16*   cpw    = (u16*)  alloc((size_t)512 * 512 * 2);
    u16*   sk0w   = (u16*)  alloc((size_t)512 * 1024 * 2);
    u16*   sk2w   = (u16*)  alloc((size_t)128 * 512 * 2);
    u16*   m1ow   = (u16*)  alloc((size_t)512 * 512 * 2);
    u16*   o1w    = (u16*)  alloc((size_t)1024 * 2560 * 2);
    u16*   o2w    = (u16*)  alloc((size_t)512 * 1024 * 2);
    // big transient buffers
    u16*   xcat   = (u16*)  alloc((size_t)BL * 1024 * 2);       // 16.8 MB
    u16*   out1   = (u16*)  alloc((size_t)BL * 2560 * 2);       // 41.9 MB
    u16*   phib   = (u16*)  alloc((size_t)BL * 512 * 2);        // 8.4 MB (bf16)
    float* phi    = (float*)alloc((size_t)BL * 512 * 4);        // 16.8 MB
    float* kesgo  = (float*)alloc((size_t)BL * 144 * 4);
    u16*   convg  = (u16*)  alloc((size_t)BL * 512 * 2);
    float* sppre  = (float*)alloc((size_t)BL * 128 * 4);
    u16*   combined = (u16*)alloc((size_t)BL * 2560 * 2);
    float* cs_o   = (float*)alloc((size_t)4 * 16 * 512 * 4);
    float* cs_x   = (float*)alloc((size_t)4 * 16 * 512 * 4);
    float* cs_m   = (float*)alloc((size_t)4 * 16 * 512 * 4);
    float* cs_wc  = (float*)alloc((size_t)4 * 16 * 512 * 4);
    float* cs_ws  = (float*)alloc((size_t)4 * 16 * 512 * 4);
    float* gni    = (float*)alloc((size_t)BL * 4);
    float* kvpart = (float*)alloc((size_t)B_ * 2 * NG_ * 1024 * 4);   // 256 KB
    // aliases onto dead buffers (liveness):
    u16*   posret = convg;                 // convg dead after mega1
    u16*   sk0g   = out1;                  // out1 dead after scan_e
    float* spc    = phi;                   // phi dead after scan_e (first 8.4 MB)
    float* sps    = phi + (size_t)BL * 128;
    float* kvcs   = (float*)phib;          // phib dead after scan_c: 4*256*2048*4 = 8.39 MB = phib size
    float* kvex   = phi + (size_t)BL * 256; // second half of phi (8.39 MB after spc/sps)
    u16*   o1g    = xcat;                  // xcat dead after mega2
    (void)ws_size; (void)in_sizes; (void)n_in; (void)out_size;

    const size_t SMEM = 49152;             // 3-slot LDS ring

    // 1. weight prep
    prep_weights<<<23307, 256, 0, stream>>>(
        tw_w, pi0_w, m1v_w, mag_w, qo_w, ke_w, ve_w, sg_w,
        pi2_w, cp_w, sk0_w, sk2_w, m1o_w, o1_w, o2_w,
        tw_b, pi0_b, m1v_b, mag_b, qo_b, ke_b, ve_b, sg_b,
        wcat1, bcat1, kesgw, kesgb, pi2w, cpw, sk0w, sk2w, m1ow, o1w, o2w);
    // 2. conv branch input + cast x into xcat (float4-vectorized, 4 d/thread)
    conv_gate<<<4096, 256, 0, stream>>>(x, lc_w, lc_b, cg_w, cg_b, convg, xcat);
    // 3. mega1: pass1 [omega | gelu(pi0) | v1 | mag | qoff] + ke/ve/sg + conv proj
    mega1<<<dim3(64, 26), 512, SMEM, stream>>>(xcat, convg, wcat1, bcat1,
                                               kesgw, kesgb, cpw, cp_b,
                                               out1, kesgo, combined);
    // 4. stage2: pi2 -> phib (bf16) + scan_a + gate scan, one dispatch
    stage2<<<769, 512, SMEM, stream>>>(out1, pi2w, pi2_b, phib,
                                       x, omega_scale, mag_scale,
                                       cs_o, cs_x, cs_m, kesgo, gni);
    // 5-6. chunked scans (512 threads: 16 rows/thread, 16 waves/CU)
    scan_c<<<512, 512, 0, stream>>>(out1, phib, omega_scale, mag_scale, cs_o,
                                    phi, cs_wc, cs_ws);
    scan_e<<<512, 512, 0, stream>>>(out1, phi, x, mag_scale, cs_m, cs_x, cs_wc, cs_ws,
                                    posret, xcat, combined);
    // 7. mega2: pos_out + sk0(gelu)
    mega2<<<dim3(64, 8), 512, SMEM, stream>>>(posret, xcat, m1ow, m1o_b,
                                              sk0w, sk0_b, combined, sk0g);
    // 8. sk2 -> storage phase pre-tanh (split-K=4, atomic f32)
    hipMemsetAsync(sppre, 0, (size_t)BL * 128 * 4, stream);
    gemm256<EPI_ATOMIC><<<dim3(64, 1, 4), 512, SMEM, stream>>>(sk0g, 512, sk2w, 512, sk2_b,
                                                               sppre, 128, 128, 128, nullptr);
    // 9-11. KV memory (chunk=8, 256 chunks/batch; two-phase hierarchical scan)
    kv_chunk<<<4 * NC_, 64, 0, stream>>>(sppre, kesgo, spc, sps, kvcs);
    kv_scan_p<<<256, 256, 0, stream>>>(kvcs, kvpart);
    kv_scan_f<<<256, 256, 0, stream>>>(kvcs, kvpart, kvex);
    kv_retrieve<<<4 * NC_, 64, 0, stream>>>(spc, sps, kesgo, gni, kvex, kvo_w, kvo_b, combined);
    // 12. layernorm in place
    ln_rows<<<8192, 320, 0, stream>>>(combined, ln_g, ln_b);
    // 13. o1 + gelu -> o1g
    gemm256<EPI_GELU_BF16><<<dim3(64, 8), 512, SMEM, stream>>>(combined, 2560, o1w, 2560, o1_b,
                                                               o1g, 1024, 1024, 2560, nullptr);
    // 14. o2 + residual -> out
    gemm256<EPI_RESID_F32><<<dim3(64, 4), 512, SMEM, stream>>>(o1g, 1024, o2w, 1024, o2_b,
                                                               out, 512, 512, 1024, x);
}

// Round 12
// 459.281 us; speedup vs baseline: 1.2599x; 1.0561x over previous
//
#include <hip/hip_runtime.h>
#include <cstdint>

typedef unsigned short u16;
typedef short short8 __attribute__((ext_vector_type(8)));
typedef float floatx4 __attribute__((ext_vector_type(4)));

#define B_ 4
#define L_ 2048
#define D_ 512
#define P_ 128
#define V_ 8
#define BL (B_ * L_)        // 8192
#define NC_ 256             // KV chunks per batch
#define CH_ 8               // KV chunk length
#define NG_ 8               // kv_scan groups (NC_/32)
#define PI_F 3.14159265358979323846f

__device__ inline u16 f2b(float f) {
    unsigned u = __float_as_uint(f);
    unsigned r = u + 0x7FFFu + ((u >> 16) & 1u);
    return (u16)(r >> 16);
}
__device__ inline float b2f(u16 h) {
    return __uint_as_float(((unsigned)h) << 16);
}
__device__ inline float gelu_f(float v) {
    return 0.5f * v * (1.0f + erff(v * 0.70710678118654752f));
}
__device__ inline float sigm(float v) {
    return 1.0f / (1.0f + __expf(-v));
}
__device__ inline float tanh_fast(float v) {
    return 1.0f - 2.0f / (1.0f + __expf(2.0f * v));
}

// async global->LDS, 16B per lane. LDS dest is wave-uniform base + lane*16.
__device__ inline void async16(const u16* g, u16* l) {
    __builtin_amdgcn_global_load_lds(
        (const __attribute__((address_space(1))) unsigned int*)g,
        (__attribute__((address_space(3))) unsigned int*)l, 16, 0, 0);
}

extern __shared__ u16 smem_dyn[];   // 49152 B: 3-slot ring of (A 8KB + B 8KB)

// ---------------------------------------------------------------------------
// 128x128-tile bf16 MFMA GEMM body, BK=32, COMPILE-TIME epilogue.
// R12 = R11 GEMM verbatim (best measured: total 485us, o1 68.8us).
// 8 waves (512 thr), 2x4 wave grid, 64x32 output per wave, acc[4][2]
// -> 16 waves/CU at 2 blocks/CU.  Measured at its LDS-BW floor (~1035
// cyc/K-step/CU vs ~1000-1200 cyc traffic floor); R4/R6/R9 structural
// alternatives all regressed -> parked.
//   * T2 XOR-swizzle (0 bank conflicts measured).
//   * Fragment double-buffer: frag t+1 ds_read during MFMA t.
//   * 3-slot ring, stage(t+3) after barrier, prefetch depth 2 K-steps.
//   * Per-iter: lgkm(0) -> vmcnt(2) -> barrier -> stage(t+3) ->
//     ds_read frag t+1 || 8xMFMA t.  Prologue 6 outstanding -> vmcnt(4).
// Requires nsteps = K/32 EVEN and >= 4 (call sites: K in {128,512,1024,2560}).
// ---------------------------------------------------------------------------
enum { EPI_F32 = 0, EPI_BF16 = 1, EPI_GELU_BF16 = 2, EPI_RESID_F32 = 3,
       EPI_PASS1 = 4, EPI_ATOMIC = 5 };

template <int EPI>
__device__ __forceinline__ void gemm_body(
    const u16* __restrict__ A, int lda,
    const u16* __restrict__ W, int ldw,
    const float* __restrict__ bias,
    void* __restrict__ Cout, int ldc, int N, int K,
    const float* __restrict__ resid, int mt, int nt)
{
    const int tid  = threadIdx.x;
    const int lane = tid & 63;
    const int wid  = tid >> 6;               // 0..7
    const int wm   = wid & 1, wn = wid >> 1; // 2 x 4 wave grid
    const int l16  = lane & 15, quad = lane >> 4;
    const int rswz = (l16 >> 1) & 3;          // read-side cg XOR ((row>>1)&3)

    floatx4 acc[4][2] = {};

    const u16* Ab = A + (size_t)(mt * 128) * lda;
    const u16* Wb = W + (size_t)(nt * 128) * ldw;

    const int srow = lane >> 2;
    // source column pre-swizzled so linear LDS write lands swizzled data
    const int scol = ((lane & 3) ^ ((srow >> 1) & 3)) * 8;
    // wave w stages A rows [16w,16w+16) and B rows [16w,16w+16) of the tile
    const u16* ga0 = Ab + (size_t)(wid * 16 + srow) * lda + scol;
    const u16* gb0 = Wb + (size_t)(wid * 16 + srow) * ldw + scol;
    const int lW = wid * 512;                 // wave-uniform LDS chunk (u16)

    const int nsteps = K >> 5;

    auto stage = [&](int t, int s) {
        u16* base = smem_dyn + s * 8192;      // 8192 u16 = 16KB per slot
        const int ko = t * 32;
        async16(ga0 + ko, base + lW);
        async16(gb0 + ko, base + 4096 + lW);
    };

    auto readfrag = [&](int slot, short8 (&a)[4], short8 (&b)[2]) {
        const u16* As = smem_dyn + slot * 8192;
        const u16* Bs = As + 4096;
#pragma unroll
        for (int i = 0; i < 4; i++)
            a[i] = *(const short8*)(&As[(wm * 64 + i * 16 + l16) * 32 + (quad ^ rswz) * 8]);
#pragma unroll
        for (int j = 0; j < 2; j++)
            b[j] = *(const short8*)(&Bs[(wn * 32 + j * 16 + l16) * 32 + (quad ^ rswz) * 8]);
    };

    auto mfma8 = [&](short8 (&a)[4], short8 (&b)[2]) {
        __builtin_amdgcn_s_setprio(1);
#pragma unroll
        for (int i = 0; i < 4; i++)
#pragma unroll
            for (int j = 0; j < 2; j++)
                acc[i][j] = __builtin_amdgcn_mfma_f32_16x16x32_bf16(a[i], b[j], acc[i][j], 0, 0, 0);
        __builtin_amdgcn_s_setprio(0);
    };

    // prologue: fill the ring (2 loads/stage -> 6 outstanding), confirm stage 0
    stage(0, 0);
    if (nsteps > 1) stage(1, 1);
    if (nsteps > 2) stage(2, 2);
    if (nsteps > 2)      asm volatile("s_waitcnt vmcnt(4)" ::: "memory");
    else if (nsteps > 1) asm volatile("s_waitcnt vmcnt(2)" ::: "memory");
    else                 asm volatile("s_waitcnt vmcnt(0)" ::: "memory");
    __builtin_amdgcn_s_barrier();
    asm volatile("" ::: "memory");

    short8 aE[4], bE[2], aO[4], bO[2];
    readfrag(0, aE, bE);

    for (int t = 0; t < nsteps; t += 2) {
        // ---- even iter: consume set E, prefetch set O ----
        asm volatile("s_waitcnt lgkmcnt(0)" ::: "memory");   // frag t in regs
        if (t + 2 < nsteps)      asm volatile("s_waitcnt vmcnt(2)" ::: "memory");
        else if (t + 1 < nsteps) asm volatile("s_waitcnt vmcnt(0)" ::: "memory");
        __builtin_amdgcn_s_barrier();
        asm volatile("" ::: "memory");
        if (t + 3 < nsteps) stage(t + 3, t % 3);
        if (t + 1 < nsteps) readfrag((t + 1) % 3, aO, bO);
        mfma8(aE, bE);
        // ---- odd iter: consume set O, prefetch set E ----
        const int t1 = t + 1;                                 // < nsteps (even nsteps)
        asm volatile("s_waitcnt lgkmcnt(0)" ::: "memory");
        if (t1 + 2 < nsteps)      asm volatile("s_waitcnt vmcnt(2)" ::: "memory");
        else if (t1 + 1 < nsteps) asm volatile("s_waitcnt vmcnt(0)" ::: "memory");
        __builtin_amdgcn_s_barrier();
        asm volatile("" ::: "memory");
        if (t1 + 3 < nsteps) stage(t1 + 3, t1 % 3);
        if (t1 + 1 < nsteps) readfrag((t1 + 1) % 3, aE, bE);
        mfma8(aO, bO);
    }

#pragma unroll
    for (int i = 0; i < 4; i++) {
#pragma unroll
        for (int j = 0; j < 2; j++) {
#pragma unroll
            for (int r = 0; r < 4; r++) {
                int grow = mt * 128 + wm * 64 + i * 16 + quad * 4 + r;
                int gcol = nt * 128 + wn * 32 + j * 16 + l16;
                if (gcol < N) {
                    float v = acc[i][j][r] + (bias ? bias[gcol] : 0.0f);
                    size_t off = (size_t)grow * ldc + gcol;
                    if (EPI == EPI_F32)            ((float*)Cout)[off] = v;
                    else if (EPI == EPI_BF16)      ((u16*)Cout)[off] = f2b(v);
                    else if (EPI == EPI_GELU_BF16) ((u16*)Cout)[off] = f2b(gelu_f(v));
                    else if (EPI == EPI_PASS1) {
                        float vv = (gcol >= 512 && gcol < 1024) ? gelu_f(v) : v;
                        ((u16*)Cout)[off] = f2b(vv);
                    }
                    else if (EPI == EPI_RESID_F32) ((float*)Cout)[off] = v + resid[off];
                    else                           atomicAdd(&((float*)Cout)[off], v);
                }
            }
        }
    }
}

// generic GEMM; grid.z = split-K slice (A,W advance by kz*K along k; bias slice 0)
template <int EPI>
__global__ __launch_bounds__(512)
void gemm256(const u16* __restrict__ A, int lda,
             const u16* __restrict__ W, int ldw,
             const float* __restrict__ bias,
             void* __restrict__ C, int ldc, int N, int K,
             const float* __restrict__ resid)
{
    int kz = blockIdx.z;
    gemm_body<EPI>(A + (size_t)kz * K, lda, W + (size_t)kz * K, ldw,
                   kz == 0 ? bias : nullptr, C, ldc, N, K, resid,
                   blockIdx.x, blockIdx.y);
}

// pass1 (N=2560,y 0..19) + ke/ve/sg (N=144,y 20..21) + conv proj (y 22..25)
__global__ __launch_bounds__(512)
void mega1(const u16* __restrict__ xcat, const u16* __restrict__ convg,
           const u16* __restrict__ wcat1, const float* __restrict__ bcat1,
           const u16* __restrict__ kesgw, const float* __restrict__ kesgb,
           const u16* __restrict__ cpw, const float* __restrict__ cp_b,
           u16* __restrict__ out1, float* __restrict__ kesgo, u16* __restrict__ combined)
{
    int y = blockIdx.y, mt = blockIdx.x;
    if (y < 20)
        gemm_body<EPI_PASS1>(xcat, 1024, wcat1, 512, bcat1, out1, 2560, 2560, 512, nullptr, mt, y);
    else if (y < 22)
        gemm_body<EPI_F32>(xcat, 1024, kesgw, 512, kesgb, kesgo, 144, 144, 512, nullptr, mt, y - 20);
    else
        gemm_body<EPI_BF16>(convg, 512, cpw, 512, cp_b, combined, 2560, 512, 512, nullptr, mt, y - 22);
}

// pos_out (y 0..3) + sk0 (y 4..7)
__global__ __launch_bounds__(512)
void mega2(const u16* __restrict__ posret, const u16* __restrict__ xcat,
           const u16* __restrict__ m1ow, const float* __restrict__ m1o_b,
           const u16* __restrict__ sk0w, const float* __restrict__ sk0_b,
           u16* __restrict__ combined, u16* __restrict__ sk0g)
{
    int y = blockIdx.y, mt = blockIdx.x;
    if (y < 4)
        gemm_body<EPI_BF16>(posret, 512, m1ow, 512, m1o_b, combined + 512, 2560, 512, 512, nullptr, mt, y);
    else
        gemm_body<EPI_GELU_BF16>(xcat, 1024, sk0w, 1024, sk0_b, sk0g, 512, 512, 1024, nullptr, mt, y - 4);
}

// ---------------------------------------------------------------------------
// Weight prep (R12: float4-vectorized).  All big-segment boundaries n0..n8
// are multiples of 4 and rows are 512 wide, so a 4-chunk never straddles a
// segment or row.  16B/lane loads, bf16x4 (uint2) stores.  Tiny bias tail
// [n8,n10) handled scalar by the trailing threads.
// ---------------------------------------------------------------------------
__global__ __launch_bounds__(256)
void prep_weights(const float* tw, const float* pi0, const float* m1v, const float* mag, const float* qo,
                  const float* ke, const float* ve, const float* sg,
                  const float* pi2, const float* cp, const float* sk0, const float* sk2,
                  const float* m1o, const float* o1, const float* o2,
                  const float* tw_b, const float* pi0_b, const float* m1v_b, const float* mag_b, const float* qo_b,
                  const float* ke_b, const float* ve_b, const float* sg_b,
                  u16* wcat1, float* bcat1, u16* kesgw, float* kesgb,
                  u16* pi2w, u16* cpw, u16* sk0w, u16* sk2w, u16* m1ow, u16* o1w, u16* o2w)
{
    const int n0 = 2560 * 512;
    const int n1 = n0 + 256 * 512;
    const int n2 = n1 + 512 * 512;
    const int n3 = n2 + 512 * 512;
    const int n4 = n3 + 512 * 1024;
    const int n5 = n4 + 128 * 512;
    const int n6 = n5 + 512 * 512;
    const int n7 = n6 + 1024 * 2560;
    const int n8 = n7 + 512 * 1024;
    const int n9 = n8 + 2560;
    const int n10 = n9 + 256;
    const int NBIG4 = n8 / 4;                 // 1490944 vector chunks

    int tid = blockIdx.x * 256 + threadIdx.x;

    auto pack4 = [](float4 v) -> uint2 {
        u16 o[4] = { f2b(v.x), f2b(v.y), f2b(v.z), f2b(v.w) };
        return *(const uint2*)o;
    };

    if (tid < NBIG4) {
        int idx = tid * 4;
        if (idx < n0) {
            int r = idx >> 9, k = idx & 511;
            const float* s = (r < 512) ? tw : (r < 1024) ? pi0 : (r < 1536) ? m1v : (r < 2048) ? mag : qo;
            *(uint2*)&wcat1[idx] = pack4(*(const float4*)&s[(r & 511) * 512 + k]);
        } else if (idx < n1) {
            int i = idx - n0; int r = i >> 9, k = i & 511;
            float4 v;
            if (r < 128)       v = *(const float4*)&ke[r * 512 + k];
            else if (r < 136)  v = *(const float4*)&ve[(r - 128) * 512 + k];
            else if (r == 136) v = *(const float4*)&sg[k];
            else               v = make_float4(0.f, 0.f, 0.f, 0.f);
            *(uint2*)&kesgw[i] = pack4(v);
        }
        else if (idx < n2) { int i = idx - n1; *(uint2*)&pi2w[i] = pack4(*(const float4*)&pi2[i]); }
        else if (idx < n3) { int i = idx - n2; *(uint2*)&cpw[i]  = pack4(*(const float4*)&cp[i]); }
        else if (idx < n4) { int i = idx - n3; *(uint2*)&sk0w[i] = pack4(*(const float4*)&sk0[i]); }
        else if (idx < n5) { int i = idx - n4; *(uint2*)&sk2w[i] = pack4(*(const float4*)&sk2[i]); }
        else if (idx < n6) { int i = idx - n5; *(uint2*)&m1ow[i] = pack4(*(const float4*)&m1o[i]); }
        else if (idx < n7) { int i = idx - n6; *(uint2*)&o1w[i]  = pack4(*(const float4*)&o1[i]); }
        else               { int i = idx - n7; *(uint2*)&o2w[i]  = pack4(*(const float4*)&o2[i]); }
    } else {
        int idx = n8 + (tid - NBIG4);         // scalar tail: biases
        if (idx < n9) {
            int i = idx - n8;
            const float* s = (i < 512) ? tw_b : (i < 1024) ? pi0_b : (i < 1536) ? m1v_b : (i < 2048) ? mag_b : qo_b;
            bcat1[i] = s[i & 511];
        } else if (idx < n10) {
            int i = idx - n9;
            kesgb[i] = (i < 128) ? ke_b[i] : (i < 136) ? ve_b[i - 128] : (i == 136) ? sg_b[0] : 0.0f;
        }
    }
}

// depthwise causal conv (K=4) gated branch + cast x into xcat cols [0,512)
// float4-vectorized — each thread computes 4 d-channels (16B/lane loads).
__global__ __launch_bounds__(256)
void conv_gate(const float* __restrict__ x,
               const float* __restrict__ lcw, const float* __restrict__ lcb,
               const float* __restrict__ cgw, const float* __restrict__ cgb,
               u16* __restrict__ out, u16* __restrict__ xcat)
{
    int idx = blockIdx.x * 256 + threadIdx.x;   // over BL*128
    int d4 = (idx & 127) * 4; int bl = idx >> 7;
    int l = bl & (L_ - 1); int b = bl >> 11;
    float4 xr[4];
#pragma unroll
    for (int k = 0; k < 4; k++) xr[k] = make_float4(0.f, 0.f, 0.f, 0.f);
#pragma unroll
    for (int k = 0; k < 4; k++) {
        int ls = l - 3 + k;
        if (ls >= 0)
            xr[k] = *(const float4*)&x[((size_t)(b * L_ + ls)) * 512 + d4];
    }
    float4 lw[4], cw[4];
#pragma unroll
    for (int j = 0; j < 4; j++) {
        lw[j] = *(const float4*)&lcw[(d4 + j) * 4];
        cw[j] = *(const float4*)&cgw[(d4 + j) * 4];
    }
    float4 lb = *(const float4*)&lcb[d4];
    float4 cb = *(const float4*)&cgb[d4];
    u16 outv[4], xcv[4];
#pragma unroll
    for (int j = 0; j < 4; j++) {
        float xk0 = (&xr[0].x)[j], xk1 = (&xr[1].x)[j],
              xk2 = (&xr[2].x)[j], xk3 = (&xr[3].x)[j];
        float a0 = (&lb.x)[j] + xk0 * (&lw[j].x)[0] + xk1 * (&lw[j].x)[1]
                              + xk2 * (&lw[j].x)[2] + xk3 * (&lw[j].x)[3];
        float a1 = sigm((&cb.x)[j] + xk0 * (&cw[j].x)[0] + xk1 * (&cw[j].x)[1]
                                   + xk2 * (&cw[j].x)[2] + xk3 * (&cw[j].x)[3]);
        outv[j] = f2b(a0 * a1);
        xcv[j]  = f2b(xk3);
    }
    *(uint2*)&out[(size_t)bl * 512 + d4]         = *(const uint2*)outv;
    *(uint2*)&xcat[(size_t)bl * 1024 + d4]       = *(const uint2*)xcv;
}

// ---------------------------------------------------------------------------
// scan_a body (512-thread version): per-chunk sums of omega/mag/x.
// blk = b(4) x dt(8) x nc(16).  8 groups of 64 lanes, 16 rows each.
// ---------------------------------------------------------------------------
__device__ __forceinline__ void scan_a_body(
    int blk, const u16* __restrict__ out1, const float* __restrict__ x,
    const float* __restrict__ oscale, const float* __restrict__ msc,
    float* __restrict__ cs_o, float* __restrict__ cs_x, float* __restrict__ cs_m)
{
    int nc = blk & 15, dt = (blk >> 4) & 7, b = blk >> 7;
    int t = threadIdx.x; int dl = t & 63, lg = t >> 6;   // lg 0..7
    int d = dt * 64 + dl;
    float os = fabsf(oscale[d]);
    float ms = fabsf(msc[0]);
    float so = 0.f, sx = 0.f, sm = 0.f;
    int l0 = nc * 128 + lg * 16;
    for (int i = 0; i < 16; i++) {
        size_t r = (size_t)(b * L_ + l0 + i);
        so += b2f(out1[r * 2560 + d]) * os;
        sm += sigm(b2f(out1[r * 2560 + 1536 + d])) * ms;
        sx += x[r * 512 + d];
    }
    __shared__ float sh[3][8][64];
    sh[0][lg][dl] = so; sh[1][lg][dl] = sx; sh[2][lg][dl] = sm;
    __syncthreads();
    if (t < 64) {
        float a = 0.f, xx = 0.f, m = 0.f;
        for (int g = 0; g < 8; g++) { a += sh[0][g][t]; xx += sh[1][g][t]; m += sh[2][g][t]; }
        size_t o = ((size_t)(b * 16 + nc)) * 512 + dt * 64 + t;
        cs_o[o] = a; cs_x[o] = xx; cs_m[o] = m;
    }
}

// store-gate scan: wave w handles batch w (waves 0..3 of the block; no barrier).
__device__ __forceinline__ void gate_body(const float* __restrict__ kesgo,
                                          float* __restrict__ gni)
{
    if (threadIdx.x >= 256) return;           // waves 4..7 idle (no barrier here)
    int b = threadIdx.x >> 6; int lane = threadIdx.x & 63;
    float v[32]; float s = 0.f;
#pragma unroll
    for (int i = 0; i < 32; i++) {
        int l = lane * 32 + i;
        v[i] = sigm(kesgo[((size_t)(b * L_ + l)) * 144 + 136]);
        s += v[i];
    }
    float sc = s;
#pragma unroll
    for (int ofs = 1; ofs < 64; ofs <<= 1) {
        float t = __shfl_up(sc, ofs, 64);
        if (lane >= ofs) sc += t;
    }
    float run = sc - s;   // exclusive prefix
#pragma unroll
    for (int i = 0; i < 32; i++) {
        run += v[i];
        gni[b * L_ + lane * 32 + i] = rsqrtf(fmaxf(run, 1.0f));
    }
}

// fused: pi2 GEMM (blocks 0..255) + scan_a (256..767) + gate scan (768)
__global__ __launch_bounds__(512)
void stage2(const u16* __restrict__ out1, const u16* __restrict__ pi2w,
            const float* __restrict__ pi2_b, u16* __restrict__ phib,
            const float* __restrict__ x, const float* __restrict__ oscale,
            const float* __restrict__ msc,
            float* __restrict__ cs_o, float* __restrict__ cs_x, float* __restrict__ cs_m,
            const float* __restrict__ kesgo, float* __restrict__ gni)
{
    int blk = blockIdx.x;
    if (blk < 256)
        gemm_body<EPI_BF16>(out1 + 512, 2560, pi2w, 512, pi2_b, phib, 512, 512, 512,
                            nullptr, blk & 63, blk >> 6);
    else if (blk < 768)
        scan_a_body(blk - 256, out1, x, oscale, msc, cs_o, cs_x, cs_m);
    else
        gate_body(kesgo, gni);
}

// scan_c (R12: 1024 threads, 8 rows/thread — chain halved again, up to
// 32 waves/CU.  16 lane-groups; cs_o interface unchanged).
__global__ __launch_bounds__(1024)
void scan_c(const u16* __restrict__ out1, const u16* __restrict__ phib,
            const float* __restrict__ oscale, const float* __restrict__ msc,
            const float* __restrict__ cs_o,
            float* __restrict__ phi, float* __restrict__ cs_wc, float* __restrict__ cs_ws)
{
    int blk = blockIdx.x;
    int nc = blk & 15, dt = (blk >> 4) & 7, b = blk >> 7;
    int t = threadIdx.x; int dl = t & 63, lg = t >> 6;   // lg 0..15
    int d = dt * 64 + dl;
    float os = fabsf(oscale[d]);
    float ms = fabsf(msc[0]);
    int l0 = nc * 128 + lg * 8;
    float so = 0.f;
    for (int i = 0; i < 8; i++) {
        size_t r = (size_t)(b * L_ + l0 + i);
        so += b2f(out1[r * 2560 + d]) * os;
    }
    __shared__ float sh[16][64];
    __shared__ float shw[2][16][64];
    sh[lg][dl] = so;
    __syncthreads();
    float pre = 0.f;
    for (int p = 0; p < nc; p++) pre += cs_o[((size_t)(b * 16 + p)) * 512 + d];
    for (int g = 0; g < lg; g++) pre += sh[g][dl];
    float cum = pre, swc = 0.f, sws = 0.f;
    for (int i = 0; i < 8; i++) {
        size_t r = (size_t)(b * L_ + l0 + i);
        cum += b2f(out1[r * 2560 + d]) * os;
        float ph = b2f(phib[r * 512 + d]) + cum;
        phi[r * 512 + d] = ph;
        float mg = sigm(b2f(out1[r * 2560 + 1536 + d])) * ms;
        float wv = mg * b2f(out1[r * 2560 + 1024 + d]);
        float s = __sinf(ph), c = __cosf(ph);
        swc += wv * c; sws += wv * s;
    }
    shw[0][lg][dl] = swc; shw[1][lg][dl] = sws;
    __syncthreads();
    if (t < 64) {
        float a = 0.f, bb = 0.f;
        for (int g = 0; g < 16; g++) { a += shw[0][g][t]; bb += shw[1][g][t]; }
        size_t o = ((size_t)(b * 16 + nc)) * 512 + dt * 64 + t;
        cs_wc[o] = a; cs_ws[o] = bb;
    }
}

// scan_e (R12: 1024 threads, 8 rows/thread — same chain halving).
__global__ __launch_bounds__(1024)
void scan_e(const u16* __restrict__ out1, const float* __restrict__ phi,
            const float* __restrict__ x, const float* __restrict__ msc,
            const float* __restrict__ cs_m, const float* __restrict__ cs_x,
            const float* __restrict__ cs_wc, const float* __restrict__ cs_ws,
            u16* __restrict__ posret, u16* __restrict__ xcat, u16* __restrict__ combined)
{
    int blk = blockIdx.x;
    int nc = blk & 15, dt = (blk >> 4) & 7, b = blk >> 7;
    int t = threadIdx.x; int dl = t & 63, lg = t >> 6;   // lg 0..15
    int d = dt * 64 + dl;
    float ms = fabsf(msc[0]);
    int l0 = nc * 128 + lg * 8;
    float sm = 0.f, swc = 0.f, sws = 0.f, sx = 0.f;
    for (int i = 0; i < 8; i++) {
        size_t r = (size_t)(b * L_ + l0 + i);
        float ph = phi[r * 512 + d];
        float mg = sigm(b2f(out1[r * 2560 + 1536 + d])) * ms;
        float wv = mg * b2f(out1[r * 2560 + 1024 + d]);
        float s = __sinf(ph), c = __cosf(ph);
        sm += mg; swc += wv * c; sws += wv * s; sx += x[r * 512 + d];
    }
    __shared__ float sh[4][16][64];
    sh[0][lg][dl] = sm; sh[1][lg][dl] = swc; sh[2][lg][dl] = sws; sh[3][lg][dl] = sx;
    __syncthreads();
    float cm = 0.f, cwc = 0.f, cws = 0.f, cx = 0.f;
    for (int p = 0; p < nc; p++) {
        size_t o = ((size_t)(b * 16 + p)) * 512 + d;
        cm += cs_m[o]; cwc += cs_wc[o]; cws += cs_ws[o]; cx += cs_x[o];
    }
    for (int g = 0; g < lg; g++) {
        cm += sh[0][g][dl]; cwc += sh[1][g][dl]; cws += sh[2][g][dl]; cx += sh[3][g][dl];
    }
    const float invsqD = 0.044194173824159216f;  // 1/sqrt(512)
    for (int i = 0; i < 8; i++) {
        int l = l0 + i;
        size_t r = (size_t)(b * L_ + l);
        float ph = phi[r * 512 + d];
        float mg = sigm(b2f(out1[r * 2560 + 1536 + d])) * ms;
        float wv = mg * b2f(out1[r * 2560 + 1024 + d]);
        float xv = x[r * 512 + d];
        float s = __sinf(ph), c = __cosf(ph);
        cm += mg; cwc += wv * c; cws += wv * s; cx += xv;
        float smag = sqrtf(cm + 1e-8f);
        float m1c = cwc / smag, m1s = cws / smag;
        float phq = ph + b2f(out1[r * 2560 + 2048 + d]);
        float sq = __sinf(phq), cq = __cosf(phq);
        float pr = (m1c * cq + m1s * sq) * invsqD;
        posret[r * 512 + d] = f2b(pr);
        xcat[r * 1024 + 512 + d] = f2b(cx / (float)(l + 1));
        combined[r * 2560 + 1536 + d] = f2b(xv * c);
        combined[r * 2560 + 2048 + d] = f2b(xv * s);
    }
}

// KV chunk-state sums + materialize sincos(storage_phase).
// NC_=256, CH_=8: 1024 blocks (4 waves/CU).  Lane t covers p=t,p+64.
__global__ __launch_bounds__(64)
void kv_chunk(const float* __restrict__ sppre, const float* __restrict__ kesgo,
              float* __restrict__ spc, float* __restrict__ sps,
              float* __restrict__ csum)
{
    int blk = blockIdx.x; int nc = blk & (NC_ - 1), b = blk >> 8;
    int t = threadIdx.x;
    float Sc[2][8] = {}, Ss[2][8] = {};
    for (int i = 0; i < CH_; i++) {
        size_t r = (size_t)(b * L_ + nc * CH_ + i);
        float sgate = sigm(kesgo[r * 144 + 136]);
        float g[8];
#pragma unroll
        for (int v = 0; v < 8; v++) g[v] = kesgo[r * 144 + 128 + v] * sgate;
#pragma unroll
        for (int j = 0; j < 2; j++) {
            int p = t + j * 64;
            float sp = tanh_fast(sppre[r * 128 + p]) * PI_F;
            float s = __sinf(sp), c = __cosf(sp);
            spc[r * 128 + p] = c; sps[r * 128 + p] = s;
#pragma unroll
            for (int v = 0; v < 8; v++) { Sc[j][v] += c * g[v]; Ss[j][v] += s * g[v]; }
        }
    }
    size_t base = (size_t)blk * 2048;
#pragma unroll
    for (int j = 0; j < 2; j++)
#pragma unroll
        for (int v = 0; v < 8; v++) {
            csum[base + (t + j * 64) * 8 + v]        = Sc[j][v];
            csum[base + 1024 + (t + j * 64) * 8 + v] = Ss[j][v];
        }
}

// two-phase kv scan.  Phase p: per-group partial sums.
__global__ __launch_bounds__(256)
void kv_scan_p(const float* __restrict__ cin, float* __restrict__ part)
{
    int t = blockIdx.x * 256 + threadIdx.x;
    int pv = t & 1023; int cs = (t >> 10) & 1; int g = (t >> 11) & (NG_ - 1);
    int b = t >> 14;
    float s = 0.f;
    for (int i = 0; i < NC_ / NG_; i++) {
        int nc = g * (NC_ / NG_) + i;
        s += cin[((size_t)(b * NC_ + nc)) * 2048 + cs * 1024 + pv];
    }
    part[((size_t)((b * 2 + cs) * NG_ + g)) * 1024 + pv] = s;
}

// Phase f: offset by prior-group partials, emit exclusive prefix for own group.
__global__ __launch_bounds__(256)
void kv_scan_f(const float* __restrict__ cin, const float* __restrict__ part,
               float* __restrict__ cex)
{
    int t = blockIdx.x * 256 + threadIdx.x;
    int pv = t & 1023; int cs = (t >> 10) & 1; int g = (t >> 11) & (NG_ - 1);
    int b = t >> 14;
    float run = 0.f;
    for (int gp = 0; gp < g; gp++)
        run += part[((size_t)((b * 2 + cs) * NG_ + gp)) * 1024 + pv];
    for (int i = 0; i < NC_ / NG_; i++) {
        int nc = g * (NC_ / NG_) + i;
        size_t o = ((size_t)(b * NC_ + nc)) * 2048 + cs * 1024 + pv;
        cex[o] = run; run += cin[o];
    }
}

// KV retrieve + fused kv_out linear -> combined cols [1024,1536)
// 1024 blocks (4 waves/CU), CH_=8 serial rows per block.
__global__ __launch_bounds__(64)
void kv_retrieve(const float* __restrict__ spc, const float* __restrict__ sps,
                 const float* __restrict__ kesgo,
                 const float* __restrict__ gni, const float* __restrict__ cex,
                 const float* __restrict__ kvo_w, const float* __restrict__ kvo_b,
                 u16* __restrict__ combined)
{
    int blk = blockIdx.x; int nc = blk & (NC_ - 1), b = blk >> 8;
    int t = threadIdx.x;
    const int nb = t * 8;                 // this lane's 8 output cols
    float wr[8][8], br[8];
#pragma unroll
    for (int n = 0; n < 8; n++) {
        *(float4*)&wr[n][0] = *(const float4*)&kvo_w[(nb + n) * 8];
        *(float4*)&wr[n][4] = *(const float4*)&kvo_w[(nb + n) * 8 + 4];
        br[n] = kvo_b[nb + n];
    }
    float Sc[2][8], Ss[2][8];
    size_t base = (size_t)blk * 2048;
#pragma unroll
    for (int j = 0; j < 2; j++)
#pragma unroll
        for (int v = 0; v < 8; v++) {
            Sc[j][v] = cex[base + (t + j * 64) * 8 + v];
            Ss[j][v] = cex[base + 1024 + (t + j * 64) * 8 + v];
        }
    for (int i = 0; i < CH_; i++) {
        size_t r = (size_t)(b * L_ + nc * CH_ + i);
        float sgate = sigm(kesgo[r * 144 + 136]);
        float g[8];
#pragma unroll
        for (int v = 0; v < 8; v++) g[v] = kesgo[r * 144 + 128 + v] * sgate;
        float part[8];
#pragma unroll
        for (int v = 0; v < 8; v++) part[v] = 0.f;
#pragma unroll
        for (int j = 0; j < 2; j++) {
            int p = t + j * 64;
            float c = spc[r * 128 + p], s = sps[r * 128 + p];
#pragma unroll
            for (int v = 0; v < 8; v++) { Sc[j][v] += c * g[v]; Ss[j][v] += s * g[v]; }
            float qp = tanh_fast(kesgo[r * 144 + p]) * PI_F;
            float sq = __sinf(qp), cq = __cosf(qp);
#pragma unroll
            for (int v = 0; v < 8; v++) part[v] += cq * Sc[j][v] + sq * Ss[j][v];
        }
#pragma unroll
        for (int ofs = 1; ofs < 64; ofs <<= 1)
#pragma unroll
            for (int v = 0; v < 8; v++) part[v] += __shfl_xor(part[v], ofs, 64);
        float scale = gni[r] * 0.08838834764831845f;   // 1/sqrt(128)
        float pv[8];
#pragma unroll
        for (int v = 0; v < 8; v++) pv[v] = part[v] * scale;
        u16 outv[8];
#pragma unroll
        for (int n = 0; n < 8; n++) {
            float a = br[n];
#pragma unroll
            for (int v = 0; v < 8; v++) a += pv[v] * wr[n][v];
            outv[n] = f2b(a);
        }
        *(uint4*)&combined[r * 2560 + 1024 + nb] = *(const uint4*)outv;
    }
}

// layernorm over 2560, in place on bf16 combined.  Block 320 (5 waves), b128 I/O.
__global__ __launch_bounds__(320)
void ln_rows(u16* __restrict__ combined, const float* __restrict__ g, const float* __restrict__ bb)
{
    size_t m = blockIdx.x; int t = threadIdx.x;   // 0..319, one oct each
    u16 vv[8];
    *(uint4*)vv = *(const uint4*)&combined[m * 2560 + t * 8];
    float f[8]; float s = 0.f, s2 = 0.f;
#pragma unroll
    for (int k = 0; k < 8; k++) { f[k] = b2f(vv[k]); s += f[k]; s2 += f[k] * f[k]; }
#pragma unroll
    for (int ofs = 1; ofs < 64; ofs <<= 1) {
        s  += __shfl_xor(s, ofs, 64);
        s2 += __shfl_xor(s2, ofs, 64);
    }
    __shared__ float shs[5], shs2[5];
    int wv = t >> 6;
    if ((t & 63) == 0) { shs[wv] = s; shs2[wv] = s2; }
    __syncthreads();
    float S = 0.f, S2 = 0.f;
#pragma unroll
    for (int i = 0; i < 5; i++) { S += shs[i]; S2 += shs2[i]; }
    float mean = S * (1.0f / 2560.0f);
    float var  = S2 * (1.0f / 2560.0f) - mean * mean;
    float rstd = rsqrtf(var + 1e-5f);
#pragma unroll
    for (int k = 0; k < 8; k++) {
        int c = t * 8 + k;
        vv[k] = f2b((f[k] - mean) * rstd * g[c] + bb[c]);
    }
    *(uint4*)&combined[m * 2560 + t * 8] = *(const uint4*)vv;
}

// ---------------------------------------------------------------------------
extern "C" void kernel_launch(void* const* d_in, const int* in_sizes, int n_in,
                              void* d_out, int out_size, void* d_ws, size_t ws_size,
                              hipStream_t stream)
{
    const float* x     = (const float*)d_in[0];
    const float* lc_w  = (const float*)d_in[1];
    const float* lc_b  = (const float*)d_in[2];
    const float* cg_w  = (const float*)d_in[3];
    const float* cg_b  = (const float*)d_in[4];
    const float* cp_w  = (const float*)d_in[5];
    const float* cp_b  = (const float*)d_in[6];
    const float* tw_w  = (const float*)d_in[7];
    const float* tw_b  = (const float*)d_in[8];
    const float* omega_scale = (const float*)d_in[9];
    const float* pi0_w = (const float*)d_in[10];
    const float* pi0_b = (const float*)d_in[11];
    const float* pi2_w = (const float*)d_in[12];
    const float* pi2_b = (const float*)d_in[13];
    const float* m1v_w = (const float*)d_in[14];
    const float* m1v_b = (const float*)d_in[15];
    const float* m1o_w = (const float*)d_in[16];
    const float* m1o_b = (const float*)d_in[17];
    const float* mag_w = (const float*)d_in[18];
    const float* mag_b = (const float*)d_in[19];
    const float* mag_scale = (const float*)d_in[20];
    const float* qo_w  = (const float*)d_in[21];
    const float* qo_b  = (const float*)d_in[22];
    const float* ke_w  = (const float*)d_in[23];
    const float* ke_b  = (const float*)d_in[24];
    const float* ve_w  = (const float*)d_in[25];
    const float* ve_b  = (const float*)d_in[26];
    const float* sk0_w = (const float*)d_in[27];
    const float* sk0_b = (const float*)d_in[28];
    const float* sk2_w = (const float*)d_in[29];
    const float* sk2_b = (const float*)d_in[30];
    const float* sg_w  = (const float*)d_in[31];
    const float* sg_b  = (const float*)d_in[32];
    const float* kvo_w = (const float*)d_in[33];
    const float* kvo_b = (const float*)d_in[34];
    const float* ln_g  = (const float*)d_in[35];
    const float* ln_b  = (const float*)d_in[36];
    const float* o1_w  = (const float*)d_in[37];
    const float* o1_b  = (const float*)d_in[38];
    const float* o2_w  = (const float*)d_in[39];
    const float* o2_b  = (const float*)d_in[40];
    float* out = (float*)d_out;

    char* base = (char*)d_ws;
    size_t off = 0;
    auto alloc = [&](size_t bytes) -> void* {
        void* p = base + off;
        off += (bytes + 255) & ~(size_t)255;
        return p;
    };

    u16*   wcat1  = (u16*)  alloc((size_t)2560 * 512 * 2);
    float* bcat1  = (float*)alloc(2560 * 4);
    u16*   kesgw  = (u16*)  alloc((size_t)256 * 512 * 2);
    float* kesgb  = (float*)alloc(256 * 4);
    u16*   pi2w   = (u16*)  alloc((size_t)512 * 512 * 2);
    u16*   cpw    = (u16*)  alloc((size_t)512 * 512 * 2);
    u16*   sk0w   = (u16*)  alloc((size_t)512 * 1024 * 2);
    u16*   sk2w   = (u16*)  alloc((size_t)128 * 512 * 2);
    u16*   m1ow   = (u16*)  alloc((size_t)512 * 512 * 2);
    u16*   o1w    = (u16*)  alloc((size_t)1024 * 2560 * 2);
    u16*   o2w    = (u16*)  alloc((size_t)512 * 1024 * 2);
    // big transient buffers
    u16*   xcat   = (u16*)  alloc((size_t)BL * 1024 * 2);       // 16.8 MB
    u16*   out1   = (u16*)  alloc((size_t)BL * 2560 * 2);       // 41.9 MB
    u16*   phib   = (u16*)  alloc((size_t)BL * 512 * 2);        // 8.4 MB (bf16)
    float* phi    = (float*)alloc((size_t)BL * 512 * 4);        // 16.8 MB
    float* kesgo  = (float*)alloc((size_t)BL * 144 * 4);
    u16*   convg  = (u16*)  alloc((size_t)BL * 512 * 2);
    float* sppre  = (float*)alloc((size_t)BL * 128 * 4);
    u16*   combined = (u16*)alloc((size_t)BL * 2560 * 2);
    float* cs_o   = (float*)alloc((size_t)4 * 16 * 512 * 4);
    float* cs_x   = (float*)alloc((size_t)4 * 16 * 512 * 4);
    float* cs_m   = (float*)alloc((size_t)4 * 16 * 512 * 4);
    float* cs_wc  = (float*)alloc((size_t)4 * 16 * 512 * 4);
    float* cs_ws  = (float*)alloc((size_t)4 * 16 * 512 * 4);
    float* gni    = (float*)alloc((size_t)BL * 4);
    float* kvpart = (float*)alloc((size_t)B_ * 2 * NG_ * 1024 * 4);   // 256 KB
    // aliases onto dead buffers (liveness):
    u16*   posret = convg;                 // convg dead after mega1
    u16*   sk0g   = out1;                  // out1 dead after scan_e
    float* spc    = phi;                   // phi dead after scan_e (first 8.4 MB)
    float* sps    = phi + (size_t)BL * 128;
    float* kvcs   = (float*)phib;          // phib dead after scan_c (8.39 MB = phib size)
    float* kvex   = phi + (size_t)BL * 256; // second half of phi (8.39 MB after spc/sps)
    u16*   o1g    = xcat;                  // xcat dead after mega2
    (void)ws_size; (void)in_sizes; (void)n_in; (void)out_size;

    const size_t SMEM = 49152;             // 3-slot LDS ring

    // 1. weight prep (float4-vectorized; 5835 blocks cover 1.49M vec + 2816 scalar)
    prep_weights<<<5835, 256, 0, stream>>>(
        tw_w, pi0_w, m1v_w, mag_w, qo_w, ke_w, ve_w, sg_w,
        pi2_w, cp_w, sk0_w, sk2_w, m1o_w, o1_w, o2_w,
        tw_b, pi0_b, m1v_b, mag_b, qo_b, ke_b, ve_b, sg_b,
        wcat1, bcat1, kesgw, kesgb, pi2w, cpw, sk0w, sk2w, m1ow, o1w, o2w);
    // 2. conv branch input + cast x into xcat (float4-vectorized, 4 d/thread)
    conv_gate<<<4096, 256, 0, stream>>>(x, lc_w, lc_b, cg_w, cg_b, convg, xcat);
    // 3. mega1: pass1 [omega | gelu(pi0) | v1 | mag | qoff] + ke/ve/sg + conv proj
    mega1<<<dim3(64, 26), 512, SMEM, stream>>>(xcat, convg, wcat1, bcat1,
                                               kesgw, kesgb, cpw, cp_b,
                                               out1, kesgo, combined);
    // 4. stage2: pi2 -> phib (bf16) + scan_a + gate scan, one dispatch
    stage2<<<769, 512, SMEM, stream>>>(out1, pi2w, pi2_b, phib,
                                       x, omega_scale, mag_scale,
                                       cs_o, cs_x, cs_m, kesgo, gni);
    // 5-6. chunked scans (1024 threads: 8 rows/thread, up to 32 waves/CU)
    scan_c<<<512, 1024, 0, stream>>>(out1, phib, omega_scale, mag_scale, cs_o,
                                     phi, cs_wc, cs_ws);
    scan_e<<<512, 1024, 0, stream>>>(out1, phi, x, mag_scale, cs_m, cs_x, cs_wc, cs_ws,
                                     posret, xcat, combined);
    // 7. mega2: pos_out + sk0(gelu)
    mega2<<<dim3(64, 8), 512, SMEM, stream>>>(posret, xcat, m1ow, m1o_b,
                                              sk0w, sk0_b, combined, sk0g);
    // 8. sk2 -> storage phase pre-tanh (split-K=4, atomic f32)
    hipMemsetAsync(sppre, 0, (size_t)BL * 128 * 4, stream);
    gemm256<EPI_ATOMIC><<<dim3(64, 1, 4), 512, SMEM, stream>>>(sk0g, 512, sk2w, 512, sk2_b,
                                                               sppre, 128, 128, 128, nullptr);
    // 9-11. KV memory (chunk=8, 256 chunks/batch; two-phase hierarchical scan)
    kv_chunk<<<4 * NC_, 64, 0, stream>>>(sppre, kesgo, spc, sps, kvcs);
    kv_scan_p<<<256, 256, 0, stream>>>(kvcs, kvpart);
    kv_scan_f<<<256, 256, 0, stream>>>(kvcs, kvpart, kvex);
    kv_retrieve<<<4 * NC_, 64, 0, stream>>>(spc, sps, kesgo, gni, kvex, kvo_w, kvo_b, combined);
    // 12. layernorm in place
    ln_rows<<<8192, 320, 0, stream>>>(combined, ln_g, ln_b);
    // 13. o1 + gelu -> o1g
    gemm256<EPI_GELU_BF16><<<dim3(64, 8), 512, SMEM, stream>>>(combined, 2560, o1w, 2560, o1_b,
                                                               o1g, 1024, 1024, 2560, nullptr);
    // 14. o2 + residual -> out
    gemm256<EPI_RESID_F32><<<dim3(64, 4), 512, SMEM, stream>>>(o1g, 1024, o2w, 1024, o2_b,
                                                               out, 512, 512, 1024, x);
}